// Round 18
// baseline (950.624 us; speedup 1.0000x reference)
//
#include <hip/hip_runtime.h>
#include <hip/hip_bf16.h>
#include <math.h>

typedef __hip_bfloat16 bf16;
typedef __attribute__((ext_vector_type(8))) short bf16x8;
typedef __attribute__((ext_vector_type(4))) float f32x4;

typedef const void __attribute__((address_space(1)))* gptr_t;
typedef void __attribute__((address_space(3)))* lptr_t;

static __device__ __forceinline__ void gload16(const void* g, void* l) {
    __builtin_amdgcn_global_load_lds((gptr_t)g, (lptr_t)l, 16, 0, 0);
}

static __device__ __forceinline__ float tofl(float x) { return x; }
static __device__ __forceinline__ float tofl(bf16 x) { return __bfloat162float(x); }
static __device__ __forceinline__ float bfbits(unsigned short u) {
    return __uint_as_float(((unsigned)u) << 16);
}

// ---------------------------------------------------------------------------
// Batched MFMA GEMM, operands K-contiguous ("TN"), global_load_lds staged,
// triple-buffered counted-vmcnt K-loop, XCD-bijective block swizzle,
// XOR bank-swizzle on staging. Wave grid 2 x (NWAVE/2); per-wave tile
// (BM/2) x (BN/(NWAVE/2)). Configs: (128,64,4) (128,128,4) (128,256,8)
// (256,256,8 = fat-tile: FM=8, 32 MFMA/barrier, 0.375 ds_read/MFMA).
//
// K%32!=0: last K-step over-reads <=16 elements past the row; BOTH A and B
// fragments are zero-masked for invalid chunks (0 x NaN = NaN otherwise).
//
//   C[z,i,j] = scale*sum_k A[(z%a_mod)*a_batch + i*lda + k]
//                    * B[(z/b_div)*b_batch + j*ldb + k] + bias[(z/b_div)*bs + j]
// k_chunk>0: z indexes K-split chunks (f32 partials).
//
// c_mode: 0 = bf16 normal store; 1 = f32 direct store;
//         2 = per-tile: tiles with j0 < t_colbase normal, j0 >= t_colbase
//             transposed (t_colbase MUST be a multiple of BN -> no straddle);
//         3 = transposed-only.
// Transposed tile: LDS C-tile Cst[col][row] pitch BM+8 (uint2 writes, uint4
// reads, both bank-spread). Mapping: row i -> (b2=i/t_rowdiv, rr=i%t_rowdiv);
//   Ct[bz*t_zbatch + b2*t_batch + (j-t_colbase)*t_ld + rr]
// (16B packs of 8 rows; requires M%8==0, t_rowdiv%8==0, t_ld%8==0).
// Requires lda%8==0, ldb%8==0, 16B-aligned bases, +64B slack per operand
// buffer. Pad rows clamped.
// ---------------------------------------------------------------------------
template<int BM, int BN, int NWAVE>
__global__ __launch_bounds__(NWAVE * 64)
void gemm_mfma2(const bf16* __restrict__ A, const bf16* __restrict__ B,
                const float* __restrict__ bias, void* __restrict__ C, int c_mode,
                int M, int N, int K,
                long a_batch, long lda, int a_mod,
                long b_batch, long ldb, int b_div,
                long bias_stride, long c_batch, long c_row,
                float scale, int k_chunk,
                bf16* __restrict__ Ct, long t_zbatch, long t_batch, long t_ld,
                int t_colbase, int t_rowdiv)
{
    constexpr int NT = NWAVE * 64;               // threads
    constexpr int WC = NWAVE / 2;                // wave cols (grid is 2 x WC)
    constexpr int WM = BM / 2;                   // per-wave M span
    constexpr int WN = BN / WC;                  // per-wave N span
    constexpr int FM = WM / 16, FN = WN / 16;
    constexpr int AL = BM / (NWAVE * 16);        // A gloads per wave
    constexpr int NBB = BN / (NWAVE * 16);       // B gloads per wave
    constexpr int P = AL + NBB;                  // gloads per wave per iter
    constexpr int CP  = BN + 4;                  // normal C-tile pitch (bf16)
    constexpr int CPT = BM + 8;                  // transposed C-tile pitch
    constexpr int BUFS = (BM + BN) * 32;         // shorts per stage buffer
    constexpr int NBUF = 3;
    constexpr int ABSZ = NBUF * BUFS * 2;
    constexpr int CSZ  = BM * CP * 2;
    constexpr int CTSZ = BN * CPT * 2;
    constexpr int CMAX = (CSZ > CTSZ) ? CSZ : CTSZ;
    constexpr int SMSZ = (CMAX > ABSZ) ? CMAX : ABSZ;
    __shared__ __align__(16) char smem[SMSZ];
    short* SA = (short*)smem;

    // ---- bijective XCD chunk swizzle (m204) ----
    const int gx = gridDim.x, gy = gridDim.y;
    const int nwg = gx * gy * (int)gridDim.z;
    const int orig = blockIdx.x + gx * (blockIdx.y + gy * blockIdx.z);
    const int qv = nwg >> 3, rv = nwg & 7;
    const int xcd = orig & 7, pos = orig >> 3;
    const int wg = (xcd < rv ? xcd * (qv + 1) : rv * (qv + 1) + (xcd - rv) * qv) + pos;
    const int bx = wg % gx, by = (wg / gx) % gy, bz = wg / (gx * gy);

    const int tid = threadIdx.x, w = tid >> 6, lane = tid & 63;
    const int wr = w / WC, wc = w % WC, lrow = lane & 15, lch = lane >> 4;
    const bf16* Ab = A + (long)(bz % a_mod) * a_batch;
    const bf16* Bb = B + (long)(bz / b_div) * b_batch;
    const int i0 = by * BM, j0 = bx * BN;

    int kstart = 0, kend = K;
    if (k_chunk > 0) {
        kstart = bz * k_chunk;
        kend = kstart + k_chunk; if (kend > K) kend = K;
    }

    f32x4 acc[FM][FN];
#pragma unroll
    for (int m = 0; m < FM; ++m)
#pragma unroll
        for (int n = 0; n < FN; ++n) acc[m][n] = (f32x4){0.f, 0.f, 0.f, 0.f};

    const int srow = lane >> 2;                          // staging row-in-16
    const int schunk = ((lane & 3) ^ (srow & 3)) * 8;    // XOR-swizzled source chunk
    const int nt = (kend - kstart + 31) >> 5;
    const bool has_tail = ((kend - kstart) & 31) != 0;
    const bf16x8 zero8 = {0, 0, 0, 0, 0, 0, 0, 0};

    // ---- hoisted staging pointers (row-clamped) + LDS dest offsets ----
    const bf16* agp[AL];
    int aoff[AL];
#pragma unroll
    for (int u = 0; u < AL; ++u) {
        int row = w * (BM / NWAVE) + u * 16 + srow;
        long gr = i0 + row; if (gr > M - 1) gr = M - 1;
        agp[u] = Ab + gr * lda + schunk;
        aoff[u] = (w * (BM / NWAVE) + u * 16) * 32;
    }
    const bf16* bgp[NBB];
    int boff[NBB];
#pragma unroll
    for (int u = 0; u < NBB; ++u) {
        int row = w * (BN / NWAVE) + u * 16 + srow;
        long gr = j0 + row; if (gr > N - 1) gr = N - 1;
        bgp[u] = Bb + gr * ldb + schunk;
        boff[u] = BM * 32 + (w * (BN / NWAVE) + u * 16) * 32;
    }
    // ---- hoisted fragment LDS read offsets (loop-invariant) ----
    const int rsw = (lch ^ (lane & 3)) * 8;   // row&3 == lane&3 for all frags
    int aro[FM], bro[FN];
#pragma unroll
    for (int m = 0; m < FM; ++m) aro[m] = (wr * WM + m * 16 + lrow) * 32 + rsw;
#pragma unroll
    for (int n = 0; n < FN; ++n) bro[n] = BM * 32 + (wc * WN + n * 16 + lrow) * 32 + rsw;

    auto stage = [&](int buf, int k0) {
        short* base = SA + buf * BUFS;
#pragma unroll
        for (int u = 0; u < AL; ++u) gload16(agp[u] + k0, base + aoff[u]);
#pragma unroll
        for (int u = 0; u < NBB; ++u) gload16(bgp[u] + k0, base + boff[u]);
    };

    stage(0, kstart);
    if (nt > 1) stage(1, kstart + 32);

    for (int t = 0; t < nt; ++t) {
        if (t + 1 < nt)
            asm volatile("s_waitcnt vmcnt(%0)" :: "i"(P) : "memory");  // tile t landed, t+1 in flight
        else
            asm volatile("s_waitcnt vmcnt(0)" ::: "memory");
        __builtin_amdgcn_s_barrier();
        __builtin_amdgcn_sched_barrier(0);

        if (t + 2 < nt) stage((t + 2) % NBUF, kstart + (t + 2) * 32);

        short* buf = SA + (t % NBUF) * BUFS;
        bf16x8 af[FM], bfv[FN];
        if (has_tail && t == nt - 1) {      // wave-uniform branch: masked tail
            const int k0 = kstart + t * 32;
            const bool kok = (k0 + lch * 8) < kend;
#pragma unroll
            for (int m = 0; m < FM; ++m) {
                af[m] = *(const bf16x8*)&buf[aro[m]];
                if (!kok) af[m] = zero8;
            }
#pragma unroll
            for (int n = 0; n < FN; ++n) {
                bfv[n] = *(const bf16x8*)&buf[bro[n]];
                if (!kok) bfv[n] = zero8;   // B mask essential: 0 x NaN = NaN
            }
        } else {                            // main path: no masking
#pragma unroll
            for (int m = 0; m < FM; ++m) af[m] = *(const bf16x8*)&buf[aro[m]];
#pragma unroll
            for (int n = 0; n < FN; ++n) bfv[n] = *(const bf16x8*)&buf[bro[n]];
        }
#pragma unroll
        for (int m = 0; m < FM; ++m)
#pragma unroll
            for (int n = 0; n < FN; ++n)
                acc[m][n] = __builtin_amdgcn_mfma_f32_16x16x32_bf16(af[m], bfv[n], acc[m][n], 0, 0, 0);
    }

    const float* bp = bias ? (bias + (long)(bz / b_div) * bias_stride) : nullptr;

    if (c_mode == 1) {  // small f32 partials: direct scalar stores
#pragma unroll
        for (int n = 0; n < FN; ++n) {
            int cc = j0 + wc * WN + n * 16 + lrow;
            if (cc >= N) continue;
            float bv = bp ? bp[cc] : 0.f;
#pragma unroll
            for (int m = 0; m < FM; ++m) {
                int rbase = i0 + wr * WM + m * 16 + lch * 4;
#pragma unroll
                for (int j = 0; j < 4; ++j) {
                    int r = rbase + j;
                    if (r >= M) continue;
                    ((float*)C)[(long)bz * c_batch + (long)r * c_row + cc] = acc[m][n][j] * scale + bv;
                }
            }
        }
        return;
    }

    __builtin_amdgcn_s_barrier();   // K-loop done in all waves before smem reuse
    short* Cs = (short*)smem;
    const bool do_tr = (c_mode == 3) || (c_mode == 2 && j0 >= t_colbase);

    if (!do_tr) {
        // ---- normal layout [row][col] pitch CP; coalesced row stores ----
#pragma unroll
        for (int n = 0; n < FN; ++n) {
            int col = wc * WN + n * 16 + lrow;
            float bv = bp ? bp[(j0 + col < N) ? (j0 + col) : (N - 1)] : 0.f;
#pragma unroll
            for (int m = 0; m < FM; ++m) {
                int rb = wr * WM + m * 16 + lch * 4;
#pragma unroll
                for (int j = 0; j < 4; ++j) {
                    bf16 hv = __float2bfloat16(acc[m][n][j] * scale + bv);
                    Cs[(rb + j) * CP + col] = *(short*)&hv;
                }
            }
        }
        __syncthreads();
        constexpr int CHR = BN / 8;
        constexpr int CH = (BM * BN) / (NT * 8);
#pragma unroll
        for (int u = 0; u < CH; ++u) {
            int e = tid + u * NT;
            int row = e / CHR, c8 = (e % CHR) * 8;
            int r = i0 + row, cc = j0 + c8;
            if (r >= M) continue;
            bf16* dst = (bf16*)C + (long)bz * c_batch + (long)r * c_row + cc;
            if (cc + 8 <= N) {
                *(uint4*)dst = *(uint4*)&Cs[row * CP + c8];
            } else {
                for (int t2 = 0; t2 < 8; ++t2)
                    if (cc + t2 < N) dst[t2] = *(bf16*)&Cs[row * CP + c8 + t2];
            }
        }
    } else {
        // ---- transposed tile: Cst[col][row] pitch CPT ----
#pragma unroll
        for (int n = 0; n < FN; ++n) {
            int col = wc * WN + n * 16 + lrow;
            float bv = bp ? bp[(j0 + col < N) ? (j0 + col) : (N - 1)] : 0.f;
#pragma unroll
            for (int m = 0; m < FM; ++m) {
                int rb = wr * WM + m * 16 + lch * 4;
                uint2 pk;
                unsigned short* ps = (unsigned short*)&pk;
#pragma unroll
                for (int j = 0; j < 4; ++j) {
                    bf16 hv = __float2bfloat16(acc[m][n][j] * scale + bv);
                    ps[j] = *(unsigned short*)&hv;
                }
                *(uint2*)&Cs[col * CPT + rb] = pk;
            }
        }
        __syncthreads();
        constexpr int CHT = (BN * (BM / 8)) / NT;
#pragma unroll
        for (int u = 0; u < CHT; ++u) {
            int e = tid + u * NT;
            int col = e / (BM / 8), r8 = e % (BM / 8);
            int j = j0 + col;
            int rb = i0 + r8 * 8;
            if (j >= N || rb >= M) continue;
            int b2 = rb / t_rowdiv;
            int rr = rb - b2 * t_rowdiv;
            long idx = (long)bz * t_zbatch + (long)b2 * t_batch + (long)(j - t_colbase) * t_ld + rr;
            *(uint4*)&Ct[idx] = *(uint4*)&Cs[col * CPT + r8 * 8];
        }
    }
}

// Tiled transpose with convert: dst[z][c][r] = src[z][r][c]
template<typename ST>
__global__ __launch_bounds__(256)
void transpose_to_bf16(const ST* __restrict__ src, bf16* __restrict__ dst,
                       int R, int C, long s_ld, long s_batch, long d_ld, long d_batch)
{
    __shared__ float t[32][33];
    const int z = blockIdx.z;
    const int tx = threadIdx.x & 31, ty = threadIdx.x >> 5;
    const int r0 = blockIdx.y << 5, c0 = blockIdx.x << 5;
    const ST* sb = src + (long)z * s_batch;
#pragma unroll
    for (int i = 0; i < 4; ++i) {
        int r = r0 + ty + i * 8, c = c0 + tx;
        if (r < R && c < C) t[ty + i * 8][tx] = tofl(sb[(long)r * s_ld + c]);
    }
    __syncthreads();
    bf16* db = dst + (long)z * d_batch;
#pragma unroll
    for (int i = 0; i < 4; ++i) {
        int dr = c0 + ty + i * 8, dc = r0 + tx;
        if (dr < C && dc < R) db[(long)dr * d_ld + dc] = __float2bfloat16(t[tx][ty + i * 8]);
    }
}

// Fused: read tokens f32 [b][l+1][h], write xbf[b][l][h] AND xbT[b][h][l] (bf16).
__global__ __launch_bounds__(256)
void convert_dual(const float* __restrict__ src, bf16* __restrict__ xbf,
                  bf16* __restrict__ xbT, int L, int tokRows)
{
    __shared__ float t[32][33];
    const int tx = threadIdx.x & 31, ty = threadIdx.x >> 5;
    const int l0 = blockIdx.y << 5, h0 = blockIdx.x << 5;
    const float* sb = src + (long)blockIdx.z * tokRows * 768 + 768;
    bf16* xb = xbf + (long)blockIdx.z * L * 768;
    bf16* xt = xbT + (long)blockIdx.z * L * 768;
#pragma unroll
    for (int i = 0; i < 4; ++i) {
        int l = l0 + ty + i * 8, h = h0 + tx;
        float v = (l < L) ? sb[(long)l * 768 + h] : 0.f;
        t[ty + i * 8][tx] = v;
        if (l < L) xb[(long)l * 768 + h] = __float2bfloat16(v);
    }
    __syncthreads();
#pragma unroll
    for (int i = 0; i < 4; ++i) {
        int h = h0 + ty + i * 8, l = l0 + tx;
        if (l < L) xt[(long)h * L + l] = __float2bfloat16(t[tx][ty + i * 8]);
    }
}

// hT[b][0:768]=tokens[b][0][:], hT[b][768:1536]=cls[b][0][:]
__global__ __launch_bounds__(256)
void build_h(const float* __restrict__ tokens, const float* __restrict__ cls,
             bf16* __restrict__ hT, int tokRows, int clsRows)
{
    int idx = blockIdx.x * 256 + threadIdx.x;
    if (idx >= 64 * 1536) return;
    int b = idx / 1536, c = idx % 1536;
    float v = (c < 768) ? tokens[(long)b * tokRows * 768 + c]
                        : cls[(long)b * clsRows * 768 + (c - 768)];
    hT[idx] = __float2bfloat16(v);
}

// In-place bf16 row softmax (f32 math), one wave per row, vectorized uint4.
__global__ __launch_bounds__(256)
void softmax_rows_bf16(bf16* __restrict__ S, long nrows, int rowlen)
{
    long row = (long)blockIdx.x * 4 + (threadIdx.x >> 6);
    if (row >= nrows) return;
    int lane = threadIdx.x & 63;
    uint4* p = (uint4*)(S + row * (long)rowlen);
    const int nch = rowlen >> 3;
    float v[2][8];
    float m = -3.4e38f;
#pragma unroll
    for (int i = 0; i < 2; ++i) {
        int c = lane + i * 64;
        if (c < nch) {
            uint4 raw = p[c];
            unsigned short* u = (unsigned short*)&raw;
#pragma unroll
            for (int j = 0; j < 8; ++j) { v[i][j] = bfbits(u[j]); m = fmaxf(m, v[i][j]); }
        }
    }
#pragma unroll
    for (int off = 32; off > 0; off >>= 1) m = fmaxf(m, __shfl_xor(m, off, 64));
    float s = 0.f;
#pragma unroll
    for (int i = 0; i < 2; ++i) {
        int c = lane + i * 64;
        if (c < nch) {
#pragma unroll
            for (int j = 0; j < 8; ++j) { v[i][j] = __expf(v[i][j] - m); s += v[i][j]; }
        }
    }
#pragma unroll
    for (int off = 32; off > 0; off >>= 1) s += __shfl_xor(s, off, 64);
    float inv = 1.f / s;
#pragma unroll
    for (int i = 0; i < 2; ++i) {
        int c = lane + i * 64;
        if (c < nch) {
            uint4 outv;
            unsigned short* u = (unsigned short*)&outv;
#pragma unroll
            for (int j = 0; j < 8; ++j) {
                bf16 hv = __float2bfloat16(v[i][j] * inv);
                u[j] = *(unsigned short*)&hv;
            }
            p[c] = outv;
        }
    }
}

// dst[i*stride + col_off + j] = bias[j] + sum_z partial[z*rows*cols + i*cols + j]
__global__ __launch_bounds__(256)
void reduce_partials(const float* __restrict__ partial, const float* __restrict__ bias,
                     float* __restrict__ dst, int nz, int rows, int cols,
                     long dst_row_stride, long dst_col_off)
{
    int idx = blockIdx.x * 256 + threadIdx.x;
    if (idx >= rows * cols) return;
    int i = idx / cols, j = idx % cols;
    float s = bias ? bias[j] : 0.f;
    long rc = (long)rows * cols;
    for (int z = 0; z < nz; ++z) s += partial[(long)z * rc + idx];
    dst[(long)i * dst_row_stride + dst_col_off + j] = s;
}

// predicts = h1 @ fnn2_w + fnn2_b -> out[:, 0:3] (row stride 2003)
__global__ __launch_bounds__(256)
void predicts_kernel(const float* __restrict__ h1, const float* __restrict__ w2,
                     const float* __restrict__ b2, float* __restrict__ out)
{
    int idx = threadIdx.x;
    if (idx >= 64 * 3) return;
    int b = idx / 3, c = idx % 3;
    float s = b2[c];
    const float* hr = h1 + (long)b * 768;
    for (int k = 0; k < 768; ++k) s = fmaf(hr[k], w2[k * 3 + c], s);
    out[(long)b * 2003 + c] = s;
}

// ---------------------------------------------------------------------------
static inline void mfma_launch(hipStream_t s, int bm, int bn,
    const bf16* A, const bf16* B, const float* bias, void* C, int c_mode,
    int M, int N, int K,
    long a_batch, long lda, int a_mod,
    long b_batch, long ldb, int b_div,
    long bias_stride, long c_batch, long c_row, float scale, int nz, int k_chunk = 0,
    bf16* Ct = nullptr, long t_zbatch = 0, long t_batch = 0, long t_ld = 0,
    int t_colbase = 0, int t_rowdiv = 8)
{
    if (bm == 256 && bn == 256) {
        dim3 g((N + 255) / 256, (M + 255) / 256, nz);
        gemm_mfma2<256, 256, 8><<<g, dim3(512), 0, s>>>(A, B, bias, C, c_mode, M, N, K,
            a_batch, lda, a_mod, b_batch, ldb, b_div, bias_stride, c_batch, c_row, scale, k_chunk,
            Ct, t_zbatch, t_batch, t_ld, t_colbase, t_rowdiv);
    } else if (bn == 256) {
        dim3 g((N + 255) / 256, (M + 127) / 128, nz);
        gemm_mfma2<128, 256, 8><<<g, dim3(512), 0, s>>>(A, B, bias, C, c_mode, M, N, K,
            a_batch, lda, a_mod, b_batch, ldb, b_div, bias_stride, c_batch, c_row, scale, k_chunk,
            Ct, t_zbatch, t_batch, t_ld, t_colbase, t_rowdiv);
    } else if (bn == 128) {
        dim3 g((N + 127) / 128, (M + 127) / 128, nz);
        gemm_mfma2<128, 128, 4><<<g, dim3(256), 0, s>>>(A, B, bias, C, c_mode, M, N, K,
            a_batch, lda, a_mod, b_batch, ldb, b_div, bias_stride, c_batch, c_row, scale, k_chunk,
            Ct, t_zbatch, t_batch, t_ld, t_colbase, t_rowdiv);
    } else {
        dim3 g((N + 63) / 64, (M + 127) / 128, nz);
        gemm_mfma2<128, 64, 4><<<g, dim3(256), 0, s>>>(A, B, bias, C, c_mode, M, N, K,
            a_batch, lda, a_mod, b_batch, ldb, b_div, bias_stride, c_batch, c_row, scale, k_chunk,
            Ct, t_zbatch, t_batch, t_ld, t_colbase, t_rowdiv);
    }
}

extern "C" void kernel_launch(void* const* d_in, const int* in_sizes, int n_in,
                              void* d_out, int out_size, void* d_ws, size_t ws_size,
                              hipStream_t stream) {
    if (n_in < 26) return;
    const float* tokens     = (const float*)d_in[0];
    const float* cls_tokens = (const float*)d_in[1];
    const float* a_qkv_w  = (const float*)d_in[2];
    const float* a_qkv_b  = (const float*)d_in[3];
    const float* af_qkv_w = (const float*)d_in[4];
    const float* af_qkv_b = (const float*)d_in[5];
    const float* b_qkv_w  = (const float*)d_in[6];
    const float* b_qkv_b  = (const float*)d_in[7];
    const float* bf_qkv_w = (const float*)d_in[8];
    const float* bf_qkv_b = (const float*)d_in[9];
    const float* atW_w = (const float*)d_in[10];
    const float* atW_b = (const float*)d_in[11];
    const float* afW_w = (const float*)d_in[12];
    const float* afW_b = (const float*)d_in[13];
    const float* btW_w = (const float*)d_in[14];
    const float* btW_b = (const float*)d_in[15];
    const float* bfW_w = (const float*)d_in[16];
    const float* bfW_b = (const float*)d_in[17];
    const float* aft_w = (const float*)d_in[18];
    const float* aft_b = (const float*)d_in[19];
    const float* bft_w = (const float*)d_in[20];
    const float* bft_b = (const float*)d_in[21];
    const float* fnn1_w = (const float*)d_in[22];
    const float* fnn1_b = (const float*)d_in[23];
    const float* fnn2_w = (const float*)d_in[24];
    const float* fnn2_b = (const float*)d_in[25];
    float* outp = (float*)d_out;
    char* base = (char*)d_ws;

    // ---- workspace byte offsets (184.4MB total < 191.9MB proven) ----
    const size_t OFF_QKV = 0;            // qk interleaved (53.5MB); later ftwT+PART+FNN
    const size_t OFF_X   = 53600064;     // xbf -> O -> vfT (26.74MB)
    const size_t OFF_XT  = 80400128;     // xbT
    const size_t OFF_O   = 107200192;    // Vt -> OfT
    const size_t OFF_SP  = 134000256;    // S/P (37.75MB: feature z=32 chunk)
    const size_t OFF_AT  = 171800256;    // aTt [64][100][L]
    const size_t OFF_AF  = 175300256;    // aFt [64][100][L]
    const size_t OFF_M   = 178800256;    // Mbf [64][10000] bf16
    const size_t OFF_W   = 180080320;    // transposed weights (~4.3MB)

    auto B16 = [&](size_t off) { return (bf16*)(base + off); };
    auto F32 = [&](size_t off) { return (float*)(base + off); };

    bf16* WqT  = B16(OFF_W);                       // flat [2304][768]
    bf16* WfT  = (bf16*)(base + OFF_W + 3538944);  // flat [3L][L]
    bf16* atWt = (bf16*)(base + OFF_W + 3982848);  // [100][768]
    bf16* afWt = (bf16*)(base + OFF_W + 4136448);  // [100][768]

    auto phase = [&](int L, const float* tok, int tokRows,
                     const float* qkvW, const float* qkvB,
                     const float* fqkvW, const float* fqkvB,
                     const float* tWw, const float* tWb,
                     const float* fWw, const float* fWb,
                     const float* ftw, const float* ftb, long colOff)
    {
        const long LH = (long)L * 768;
        const long LL = (long)L * L;
        const int  L2 = 2 * L;                    // 544 or 512 (both %8==0)
        bf16* qkv = B16(OFF_QKV);                 // token: [64L][1536]; feature: [64*768][2L]
        bf16* q = qkv, *k = qkv + 768;            // token slices (lda 1536)
        bf16* qf = qkv, *kf = qkv + L;            // feature slices (lda 2L)
        bf16* xbf = B16(OFF_X);                   // -> later O, then vfT
        bf16* O   = B16(OFF_X);
        bf16* vfT = B16(OFF_X);
        bf16* xbT = B16(OFF_XT);
        bf16* Vt  = B16(OFF_O);                   // -> later OfT
        bf16* OfT = B16(OFF_O);
        bf16* SP  = B16(OFF_SP);
        bf16* aTt = B16(OFF_AT);
        bf16* aFt = B16(OFF_AF);
        bf16* Mbf = B16(OFF_M);
        bf16* ftwT  = B16(OFF_QKV);                 // [1000][10000], qkv dead by then
        float* PART = F32(OFF_QKV + 20000064);      // 32 x [64][1000] f32
        const int Lg = (L + 31) / 32;
        const float rsH = 1.0f / sqrtf(768.0f);
        const float rsL = 1.0f / sqrtf((float)L);

        // fused convert (xbf + xbT in one pass) / weight transposes
        convert_dual<<<dim3(24, Lg, 64), 256, 0, stream>>>(tok, xbf, xbT, L, tokRows);
        transpose_to_bf16<float><<<dim3(24, 24, 3), 256, 0, stream>>>(qkvW, WqT, 768, 768, 768, 589824, 768, 589824);
        transpose_to_bf16<float><<<dim3(Lg, Lg, 3), 256, 0, stream>>>(fqkvW, WfT, L, L, L, LL, L, LL);
        transpose_to_bf16<float><<<dim3(4, 24, 1), 256, 0, stream>>>(tWw, atWt, 768, 100, 100, 0, 768, 0);
        transpose_to_bf16<float><<<dim3(4, 24, 1), 256, 0, stream>>>(fWw, afWt, 768, 100, 100, 0, 768, 0);

        // ---- token branch: merged QKV, mode 2, fat 256x256 tile (M=64L exact)
        //      qk cols -> qkv[64L][1536]; v cols -> Vt[b][h][l] transposed ----
        mfma_launch(stream, 256, 256, xbf, WqT, qkvB, qkv, 2, 64 * L, 2304, 768,
                    0, 768, 1, 0, 768, 1, 0, 0, 1536, 1.0f, 1, 0,
                    Vt, 0, LH, L, 1536, L);
        mfma_launch(stream, 128, 64, q, k, nullptr, SP, 0, L, L, 768,
                    (long)L * 1536, 1536, 64, (long)L * 1536, 1536, 1, 0, LL, L, rsH, 64);
        softmax_rows_bf16<<<dim3((unsigned)((64L * L + 3) / 4)), 256, 0, stream>>>(SP, 64L * L, L);
        mfma_launch(stream, 128, 256, SP, Vt, nullptr, O, 0, L, 768, L,   // O overwrites xbf (dead)
                    LL, L, 64, LH, L, 1, 0, LH, 768, 1.0f, 64);
        mfma_launch(stream, 128, 64, O, atWt, tWb, nullptr, 3, 64 * L, 100, 768,  // aT -> aTt transposed
                    0, 768, 1, 0, 768, 1, 0, 0, 100, 1.0f, 1, 0,
                    aTt, 0, (long)100 * L, L, 0, L);

        // ---- feature branch: qk_f (normal) + v_f (mode-3 -> vfT[b][l][h]) ----
        mfma_launch(stream, 128, 128, xbT, WfT, fqkvB, qkv, 0, 64 * 768, L2, L,
                    0, L, 1, 0, L, 1, 0, 0, L2, 1.0f, 1);
        mfma_launch(stream, 128, 128, xbT, WfT + (long)L2 * L, fqkvB + L2, nullptr, 3, 64 * 768, L, L,
                    0, L, 1, 0, L, 1, 0, 0, 0, 1.0f, 1, 0,
                    vfT, 0, LH, 768, 0, 768);                     // vfT overwrites O (dead)
        for (int c = 0; c < 2; ++c) {   // 32-batch chunks (S chunk 37.7MB, L3-resident)
            long coA = (long)c * 32 * 768 * L2;
            long coV = (long)c * 32 * LH;
            mfma_launch(stream, 256, 256, qf + coA, kf + coA, nullptr, SP, 0, 768, 768, L,
                        768L * L2, L2, 32, 768L * L2, L2, 1, 0, 589824, 768, rsL, 32);
            softmax_rows_bf16<<<dim3(32 * 768 / 4), 256, 0, stream>>>(SP, 32L * 768, 768);
            // PV_f swapped: OfT[l][h] = sum_{h'} vfT[l][h'] * P[h][h']  (mode 0)
            mfma_launch(stream, 128, 256, vfT + coV, SP, nullptr, OfT + coV, 0, L, 768, 768,
                        LH, 768, 32, 589824, 768, 1, 0, LH, 768, 1.0f, 32);
        }
        mfma_launch(stream, 128, 64, OfT, afWt, fWb, nullptr, 3, 64 * L, 100, 768,  // aF -> aFt transposed
                    0, 768, 1, 0, 768, 1, 0, 0, 100, 1.0f, 1, 0,
                    aFt, 0, (long)100 * L, L, 0, L);

        // ---- einsum + final projection ----
        mfma_launch(stream, 128, 128, aTt, aFt, nullptr, Mbf, 0, 100, 100, L,
                    (long)100 * L, L, 64, (long)100 * L, L, 1, 0, 10000, 100, 1.0f, 64);
        transpose_to_bf16<float><<<dim3(32, 313, 1), 256, 0, stream>>>(ftw, ftwT, 10000, 1000, 1000, 0, 10000, 0);
        mfma_launch(stream, 128, 128, Mbf, ftwT, nullptr, PART, 1, 64, 1000, 10000,
                    0, 10000, 1, 0, 10000, 1, 0, 64000, 1000, 1.0f, 32, 320);
        reduce_partials<<<dim3((64 * 1000 + 255) / 256), 256, 0, stream>>>(
            PART, ftb, outp, 32, 64, 1000, 2003, colOff);
    };

    phase(272, tokens,     273, a_qkv_w, a_qkv_b, af_qkv_w, af_qkv_b,
          atW_w, atW_b, afW_w, afW_b, aft_w, aft_b, 3);
    phase(256, cls_tokens, 257, b_qkv_w, b_qkv_b, bf_qkv_w, bf_qkv_b,
          btW_w, btW_b, bfW_w, bfW_b, bft_w, bft_b, 1003);

    // ---- FNN head via MFMA (OFF_QKV region is dead now) ----
    bf16* hT     = B16(OFF_QKV);                   // [64][1536]
    bf16* fnn1T  = (bf16*)(base + OFF_QKV + 262144);   // [768][1536]
    float* PARTF = F32(OFF_QKV + 2621504);         // 6 x [64][768]
    float* h1    = F32(OFF_QKV + 3801216);         // [64][768]
    build_h<<<dim3((64 * 1536 + 255) / 256), 256, 0, stream>>>(tokens, cls_tokens, hT, 273, 257);
    transpose_to_bf16<float><<<dim3(24, 48, 1), 256, 0, stream>>>(fnn1_w, fnn1T, 1536, 768, 768, 0, 1536, 0);
    mfma_launch(stream, 128, 128, hT, fnn1T, nullptr, PARTF, 1, 64, 768, 1536,
                0, 1536, 1, 0, 1536, 1, 0, 49152, 768, 1.0f, 6, 256);
    reduce_partials<<<dim3((64 * 768 + 255) / 256), 256, 0, stream>>>(
        PARTF, fnn1_b, h1, 6, 64, 768, 768, 0);
    predicts_kernel<<<dim3(1), 256, 0, stream>>>(h1, fnn2_w, fnn2_b, outp);
}

// Round 19
// 911.298 us; speedup vs baseline: 1.0432x; 1.0432x over previous
//
#include <hip/hip_runtime.h>
#include <hip/hip_bf16.h>
#include <math.h>

typedef __hip_bfloat16 bf16;
typedef __attribute__((ext_vector_type(8))) short bf16x8;
typedef __attribute__((ext_vector_type(4))) float f32x4;

typedef const void __attribute__((address_space(1)))* gptr_t;
typedef void __attribute__((address_space(3)))* lptr_t;

static __device__ __forceinline__ void gload16(const void* g, void* l) {
    __builtin_amdgcn_global_load_lds((gptr_t)g, (lptr_t)l, 16, 0, 0);
}

static __device__ __forceinline__ float tofl(float x) { return x; }
static __device__ __forceinline__ float tofl(bf16 x) { return __bfloat162float(x); }
static __device__ __forceinline__ float bfbits(unsigned short u) {
    return __uint_as_float(((unsigned)u) << 16);
}

// ---------------------------------------------------------------------------
// Batched MFMA GEMM, operands K-contiguous ("TN"), global_load_lds staged,
// triple-buffered counted-vmcnt K-loop, XCD-bijective block swizzle,
// XOR bank-swizzle on staging. Wave grid 2 x (NWAVE/2); per-wave tile
// (BM/2) x (BN/(NWAVE/2)). Configs: (128,64,4) (128,128,4) (128,256,8).
// (256-tile BM rejected: 1 block/CU starves the 2-barrier skeleton, r18.)
//
// K%32!=0: last K-step over-reads <=16 elements past the row; BOTH A and B
// fragments are zero-masked for invalid chunks (0 x NaN = NaN otherwise).
//
//   C[z,i,j] = scale*sum_k A[(z%a_mod)*a_batch + i*lda + k]
//                    * B[(z/b_div)*b_batch + j*ldb + k] + bias[(z/b_div)*bs + j]
// k_chunk>0: z indexes K-split chunks (f32 partials).
//
// c_mode: 0 = bf16 normal store; 1 = f32 direct store;
//         2 = per-tile: tiles with j0 < t_colbase normal, j0 >= t_colbase
//             transposed (t_colbase MUST be a multiple of BN -> no straddle);
//         3 = transposed-only.
// Transposed tile: LDS C-tile Cst[col][row] pitch BM+8 (uint2 writes, uint4
// reads, both bank-spread). Mapping: row i -> (b2=i/t_rowdiv, rr=i%t_rowdiv);
//   Ct[bz*t_zbatch + b2*t_batch + (j-t_colbase)*t_ld + rr]
// (16B packs of 8 rows; requires M%8==0, t_rowdiv%8==0, t_ld%8==0).
// Requires lda%8==0, ldb%8==0, 16B-aligned bases, +64B slack per operand
// buffer. Pad rows clamped.
// ---------------------------------------------------------------------------
template<int BM, int BN, int NWAVE>
__global__ __launch_bounds__(NWAVE * 64)
void gemm_mfma2(const bf16* __restrict__ A, const bf16* __restrict__ B,
                const float* __restrict__ bias, void* __restrict__ C, int c_mode,
                int M, int N, int K,
                long a_batch, long lda, int a_mod,
                long b_batch, long ldb, int b_div,
                long bias_stride, long c_batch, long c_row,
                float scale, int k_chunk,
                bf16* __restrict__ Ct, long t_zbatch, long t_batch, long t_ld,
                int t_colbase, int t_rowdiv)
{
    constexpr int NT = NWAVE * 64;               // threads
    constexpr int WC = NWAVE / 2;                // wave cols (grid is 2 x WC)
    constexpr int WM = BM / 2;                   // per-wave M span
    constexpr int WN = BN / WC;                  // per-wave N span
    constexpr int FM = WM / 16, FN = WN / 16;
    constexpr int AL = BM / (NWAVE * 16);        // A gloads per wave
    constexpr int NBB = BN / (NWAVE * 16);       // B gloads per wave
    constexpr int P = AL + NBB;                  // gloads per wave per iter
    constexpr int CP  = BN + 4;                  // normal C-tile pitch (bf16)
    constexpr int CPT = BM + 8;                  // transposed C-tile pitch
    constexpr int BUFS = (BM + BN) * 32;         // shorts per stage buffer
    constexpr int NBUF = 3;
    constexpr int ABSZ = NBUF * BUFS * 2;
    constexpr int CSZ  = BM * CP * 2;
    constexpr int CTSZ = BN * CPT * 2;
    constexpr int CMAX = (CSZ > CTSZ) ? CSZ : CTSZ;
    constexpr int SMSZ = (CMAX > ABSZ) ? CMAX : ABSZ;
    __shared__ __align__(16) char smem[SMSZ];
    short* SA = (short*)smem;

    // ---- bijective XCD chunk swizzle (m204) ----
    const int gx = gridDim.x, gy = gridDim.y;
    const int nwg = gx * gy * (int)gridDim.z;
    const int orig = blockIdx.x + gx * (blockIdx.y + gy * blockIdx.z);
    const int qv = nwg >> 3, rv = nwg & 7;
    const int xcd = orig & 7, pos = orig >> 3;
    const int wg = (xcd < rv ? xcd * (qv + 1) : rv * (qv + 1) + (xcd - rv) * qv) + pos;
    const int bx = wg % gx, by = (wg / gx) % gy, bz = wg / (gx * gy);

    const int tid = threadIdx.x, w = tid >> 6, lane = tid & 63;
    const int wr = w / WC, wc = w % WC, lrow = lane & 15, lch = lane >> 4;
    const bf16* Ab = A + (long)(bz % a_mod) * a_batch;
    const bf16* Bb = B + (long)(bz / b_div) * b_batch;
    const int i0 = by * BM, j0 = bx * BN;

    int kstart = 0, kend = K;
    if (k_chunk > 0) {
        kstart = bz * k_chunk;
        kend = kstart + k_chunk; if (kend > K) kend = K;
    }

    f32x4 acc[FM][FN];
#pragma unroll
    for (int m = 0; m < FM; ++m)
#pragma unroll
        for (int n = 0; n < FN; ++n) acc[m][n] = (f32x4){0.f, 0.f, 0.f, 0.f};

    const int srow = lane >> 2;                          // staging row-in-16
    const int schunk = ((lane & 3) ^ (srow & 3)) * 8;    // XOR-swizzled source chunk
    const int nt = (kend - kstart + 31) >> 5;
    const bool has_tail = ((kend - kstart) & 31) != 0;
    const bf16x8 zero8 = {0, 0, 0, 0, 0, 0, 0, 0};

    // ---- hoisted staging pointers (row-clamped) + LDS dest offsets ----
    const bf16* agp[AL];
    int aoff[AL];
#pragma unroll
    for (int u = 0; u < AL; ++u) {
        int row = w * (BM / NWAVE) + u * 16 + srow;
        long gr = i0 + row; if (gr > M - 1) gr = M - 1;
        agp[u] = Ab + gr * lda + schunk;
        aoff[u] = (w * (BM / NWAVE) + u * 16) * 32;
    }
    const bf16* bgp[NBB];
    int boff[NBB];
#pragma unroll
    for (int u = 0; u < NBB; ++u) {
        int row = w * (BN / NWAVE) + u * 16 + srow;
        long gr = j0 + row; if (gr > N - 1) gr = N - 1;
        bgp[u] = Bb + gr * ldb + schunk;
        boff[u] = BM * 32 + (w * (BN / NWAVE) + u * 16) * 32;
    }
    // ---- hoisted fragment LDS read offsets (loop-invariant) ----
    const int rsw = (lch ^ (lane & 3)) * 8;   // row&3 == lane&3 for all frags
    int aro[FM], bro[FN];
#pragma unroll
    for (int m = 0; m < FM; ++m) aro[m] = (wr * WM + m * 16 + lrow) * 32 + rsw;
#pragma unroll
    for (int n = 0; n < FN; ++n) bro[n] = BM * 32 + (wc * WN + n * 16 + lrow) * 32 + rsw;

    auto stage = [&](int buf, int k0) {
        short* base = SA + buf * BUFS;
#pragma unroll
        for (int u = 0; u < AL; ++u) gload16(agp[u] + k0, base + aoff[u]);
#pragma unroll
        for (int u = 0; u < NBB; ++u) gload16(bgp[u] + k0, base + boff[u]);
    };

    stage(0, kstart);
    if (nt > 1) stage(1, kstart + 32);

    for (int t = 0; t < nt; ++t) {
        if (t + 1 < nt)
            asm volatile("s_waitcnt vmcnt(%0)" :: "i"(P) : "memory");  // tile t landed, t+1 in flight
        else
            asm volatile("s_waitcnt vmcnt(0)" ::: "memory");
        __builtin_amdgcn_s_barrier();
        __builtin_amdgcn_sched_barrier(0);

        if (t + 2 < nt) stage((t + 2) % NBUF, kstart + (t + 2) * 32);

        short* buf = SA + (t % NBUF) * BUFS;
        bf16x8 af[FM], bfv[FN];
        if (has_tail && t == nt - 1) {      // wave-uniform branch: masked tail
            const int k0 = kstart + t * 32;
            const bool kok = (k0 + lch * 8) < kend;
#pragma unroll
            for (int m = 0; m < FM; ++m) {
                af[m] = *(const bf16x8*)&buf[aro[m]];
                if (!kok) af[m] = zero8;
            }
#pragma unroll
            for (int n = 0; n < FN; ++n) {
                bfv[n] = *(const bf16x8*)&buf[bro[n]];
                if (!kok) bfv[n] = zero8;   // B mask essential: 0 x NaN = NaN
            }
        } else {                            // main path: no masking
#pragma unroll
            for (int m = 0; m < FM; ++m) af[m] = *(const bf16x8*)&buf[aro[m]];
#pragma unroll
            for (int n = 0; n < FN; ++n) bfv[n] = *(const bf16x8*)&buf[bro[n]];
        }
#pragma unroll
        for (int m = 0; m < FM; ++m)
#pragma unroll
            for (int n = 0; n < FN; ++n)
                acc[m][n] = __builtin_amdgcn_mfma_f32_16x16x32_bf16(af[m], bfv[n], acc[m][n], 0, 0, 0);
    }

    const float* bp = bias ? (bias + (long)(bz / b_div) * bias_stride) : nullptr;

    if (c_mode == 1) {  // small f32 partials: direct scalar stores
#pragma unroll
        for (int n = 0; n < FN; ++n) {
            int cc = j0 + wc * WN + n * 16 + lrow;
            if (cc >= N) continue;
            float bv = bp ? bp[cc] : 0.f;
#pragma unroll
            for (int m = 0; m < FM; ++m) {
                int rbase = i0 + wr * WM + m * 16 + lch * 4;
#pragma unroll
                for (int j = 0; j < 4; ++j) {
                    int r = rbase + j;
                    if (r >= M) continue;
                    ((float*)C)[(long)bz * c_batch + (long)r * c_row + cc] = acc[m][n][j] * scale + bv;
                }
            }
        }
        return;
    }

    __builtin_amdgcn_s_barrier();   // K-loop done in all waves before smem reuse
    short* Cs = (short*)smem;
    const bool do_tr = (c_mode == 3) || (c_mode == 2 && j0 >= t_colbase);

    if (!do_tr) {
        // ---- normal layout [row][col] pitch CP; coalesced row stores ----
#pragma unroll
        for (int n = 0; n < FN; ++n) {
            int col = wc * WN + n * 16 + lrow;
            float bv = bp ? bp[(j0 + col < N) ? (j0 + col) : (N - 1)] : 0.f;
#pragma unroll
            for (int m = 0; m < FM; ++m) {
                int rb = wr * WM + m * 16 + lch * 4;
#pragma unroll
                for (int j = 0; j < 4; ++j) {
                    bf16 hv = __float2bfloat16(acc[m][n][j] * scale + bv);
                    Cs[(rb + j) * CP + col] = *(short*)&hv;
                }
            }
        }
        __syncthreads();
        constexpr int CHR = BN / 8;
        constexpr int CH = (BM * BN) / (NT * 8);
#pragma unroll
        for (int u = 0; u < CH; ++u) {
            int e = tid + u * NT;
            int row = e / CHR, c8 = (e % CHR) * 8;
            int r = i0 + row, cc = j0 + c8;
            if (r >= M) continue;
            bf16* dst = (bf16*)C + (long)bz * c_batch + (long)r * c_row + cc;
            if (cc + 8 <= N) {
                *(uint4*)dst = *(uint4*)&Cs[row * CP + c8];
            } else {
                for (int t2 = 0; t2 < 8; ++t2)
                    if (cc + t2 < N) dst[t2] = *(bf16*)&Cs[row * CP + c8 + t2];
            }
        }
    } else {
        // ---- transposed tile: Cst[col][row] pitch CPT ----
#pragma unroll
        for (int n = 0; n < FN; ++n) {
            int col = wc * WN + n * 16 + lrow;
            float bv = bp ? bp[(j0 + col < N) ? (j0 + col) : (N - 1)] : 0.f;
#pragma unroll
            for (int m = 0; m < FM; ++m) {
                int rb = wr * WM + m * 16 + lch * 4;
                uint2 pk;
                unsigned short* ps = (unsigned short*)&pk;
#pragma unroll
                for (int j = 0; j < 4; ++j) {
                    bf16 hv = __float2bfloat16(acc[m][n][j] * scale + bv);
                    ps[j] = *(unsigned short*)&hv;
                }
                *(uint2*)&Cs[col * CPT + rb] = pk;
            }
        }
        __syncthreads();
        constexpr int CHT = (BN * (BM / 8)) / NT;
#pragma unroll
        for (int u = 0; u < CHT; ++u) {
            int e = tid + u * NT;
            int col = e / (BM / 8), r8 = e % (BM / 8);
            int j = j0 + col;
            int rb = i0 + r8 * 8;
            if (j >= N || rb >= M) continue;
            int b2 = rb / t_rowdiv;
            int rr = rb - b2 * t_rowdiv;
            long idx = (long)bz * t_zbatch + (long)b2 * t_batch + (long)(j - t_colbase) * t_ld + rr;
            *(uint4*)&Ct[idx] = *(uint4*)&Cs[col * CPT + r8 * 8];
        }
    }
}

// Tiled transpose with convert: dst[z][c][r] = src[z][r][c]
template<typename ST>
__global__ __launch_bounds__(256)
void transpose_to_bf16(const ST* __restrict__ src, bf16* __restrict__ dst,
                       int R, int C, long s_ld, long s_batch, long d_ld, long d_batch)
{
    __shared__ float t[32][33];
    const int z = blockIdx.z;
    const int tx = threadIdx.x & 31, ty = threadIdx.x >> 5;
    const int r0 = blockIdx.y << 5, c0 = blockIdx.x << 5;
    const ST* sb = src + (long)z * s_batch;
#pragma unroll
    for (int i = 0; i < 4; ++i) {
        int r = r0 + ty + i * 8, c = c0 + tx;
        if (r < R && c < C) t[ty + i * 8][tx] = tofl(sb[(long)r * s_ld + c]);
    }
    __syncthreads();
    bf16* db = dst + (long)z * d_batch;
#pragma unroll
    for (int i = 0; i < 4; ++i) {
        int dr = c0 + ty + i * 8, dc = r0 + tx;
        if (dr < C && dc < R) db[(long)dr * d_ld + dc] = __float2bfloat16(t[tx][ty + i * 8]);
    }
}

// Fused: read tokens f32 [b][l+1][h], write xbf[b][l][h] AND xbT[b][h][l] (bf16).
__global__ __launch_bounds__(256)
void convert_dual(const float* __restrict__ src, bf16* __restrict__ xbf,
                  bf16* __restrict__ xbT, int L, int tokRows)
{
    __shared__ float t[32][33];
    const int tx = threadIdx.x & 31, ty = threadIdx.x >> 5;
    const int l0 = blockIdx.y << 5, h0 = blockIdx.x << 5;
    const float* sb = src + (long)blockIdx.z * tokRows * 768 + 768;
    bf16* xb = xbf + (long)blockIdx.z * L * 768;
    bf16* xt = xbT + (long)blockIdx.z * L * 768;
#pragma unroll
    for (int i = 0; i < 4; ++i) {
        int l = l0 + ty + i * 8, h = h0 + tx;
        float v = (l < L) ? sb[(long)l * 768 + h] : 0.f;
        t[ty + i * 8][tx] = v;
        if (l < L) xb[(long)l * 768 + h] = __float2bfloat16(v);
    }
    __syncthreads();
#pragma unroll
    for (int i = 0; i < 4; ++i) {
        int h = h0 + ty + i * 8, l = l0 + tx;
        if (l < L) xt[(long)h * L + l] = __float2bfloat16(t[tx][ty + i * 8]);
    }
}

// hT[b][0:768]=tokens[b][0][:], hT[b][768:1536]=cls[b][0][:]
__global__ __launch_bounds__(256)
void build_h(const float* __restrict__ tokens, const float* __restrict__ cls,
             bf16* __restrict__ hT, int tokRows, int clsRows)
{
    int idx = blockIdx.x * 256 + threadIdx.x;
    if (idx >= 64 * 1536) return;
    int b = idx / 1536, c = idx % 1536;
    float v = (c < 768) ? tokens[(long)b * tokRows * 768 + c]
                        : cls[(long)b * clsRows * 768 + (c - 768)];
    hT[idx] = __float2bfloat16(v);
}

// In-place bf16 row softmax (f32 math), one wave per row, vectorized uint4.
__global__ __launch_bounds__(256)
void softmax_rows_bf16(bf16* __restrict__ S, long nrows, int rowlen)
{
    long row = (long)blockIdx.x * 4 + (threadIdx.x >> 6);
    if (row >= nrows) return;
    int lane = threadIdx.x & 63;
    uint4* p = (uint4*)(S + row * (long)rowlen);
    const int nch = rowlen >> 3;
    float v[2][8];
    float m = -3.4e38f;
#pragma unroll
    for (int i = 0; i < 2; ++i) {
        int c = lane + i * 64;
        if (c < nch) {
            uint4 raw = p[c];
            unsigned short* u = (unsigned short*)&raw;
#pragma unroll
            for (int j = 0; j < 8; ++j) { v[i][j] = bfbits(u[j]); m = fmaxf(m, v[i][j]); }
        }
    }
#pragma unroll
    for (int off = 32; off > 0; off >>= 1) m = fmaxf(m, __shfl_xor(m, off, 64));
    float s = 0.f;
#pragma unroll
    for (int i = 0; i < 2; ++i) {
        int c = lane + i * 64;
        if (c < nch) {
#pragma unroll
            for (int j = 0; j < 8; ++j) { v[i][j] = __expf(v[i][j] - m); s += v[i][j]; }
        }
    }
#pragma unroll
    for (int off = 32; off > 0; off >>= 1) s += __shfl_xor(s, off, 64);
    float inv = 1.f / s;
#pragma unroll
    for (int i = 0; i < 2; ++i) {
        int c = lane + i * 64;
        if (c < nch) {
            uint4 outv;
            unsigned short* u = (unsigned short*)&outv;
#pragma unroll
            for (int j = 0; j < 8; ++j) {
                bf16 hv = __float2bfloat16(v[i][j] * inv);
                u[j] = *(unsigned short*)&hv;
            }
            p[c] = outv;
        }
    }
}

// dst[i*stride + col_off + j] = bias[j] + sum_z partial[z*rows*cols + i*cols + j]
__global__ __launch_bounds__(256)
void reduce_partials(const float* __restrict__ partial, const float* __restrict__ bias,
                     float* __restrict__ dst, int nz, int rows, int cols,
                     long dst_row_stride, long dst_col_off)
{
    int idx = blockIdx.x * 256 + threadIdx.x;
    if (idx >= rows * cols) return;
    int i = idx / cols, j = idx % cols;
    float s = bias ? bias[j] : 0.f;
    long rc = (long)rows * cols;
    for (int z = 0; z < nz; ++z) s += partial[(long)z * rc + idx];
    dst[(long)i * dst_row_stride + dst_col_off + j] = s;
}

// predicts = h1 @ fnn2_w + fnn2_b -> out[:, 0:3] (row stride 2003)
__global__ __launch_bounds__(256)
void predicts_kernel(const float* __restrict__ h1, const float* __restrict__ w2,
                     const float* __restrict__ b2, float* __restrict__ out)
{
    int idx = threadIdx.x;
    if (idx >= 64 * 3) return;
    int b = idx / 3, c = idx % 3;
    float s = b2[c];
    const float* hr = h1 + (long)b * 768;
    for (int k = 0; k < 768; ++k) s = fmaf(hr[k], w2[k * 3 + c], s);
    out[(long)b * 2003 + c] = s;
}

// ---------------------------------------------------------------------------
static inline void mfma_launch(hipStream_t s, int bn,
    const bf16* A, const bf16* B, const float* bias, void* C, int c_mode,
    int M, int N, int K,
    long a_batch, long lda, int a_mod,
    long b_batch, long ldb, int b_div,
    long bias_stride, long c_batch, long c_row, float scale, int nz, int k_chunk = 0,
    bf16* Ct = nullptr, long t_zbatch = 0, long t_batch = 0, long t_ld = 0,
    int t_colbase = 0, int t_rowdiv = 8)
{
    if (bn == 256) {
        dim3 g((N + 255) / 256, (M + 127) / 128, nz);
        gemm_mfma2<128, 256, 8><<<g, dim3(512), 0, s>>>(A, B, bias, C, c_mode, M, N, K,
            a_batch, lda, a_mod, b_batch, ldb, b_div, bias_stride, c_batch, c_row, scale, k_chunk,
            Ct, t_zbatch, t_batch, t_ld, t_colbase, t_rowdiv);
    } else if (bn == 128) {
        dim3 g((N + 127) / 128, (M + 127) / 128, nz);
        gemm_mfma2<128, 128, 4><<<g, dim3(256), 0, s>>>(A, B, bias, C, c_mode, M, N, K,
            a_batch, lda, a_mod, b_batch, ldb, b_div, bias_stride, c_batch, c_row, scale, k_chunk,
            Ct, t_zbatch, t_batch, t_ld, t_colbase, t_rowdiv);
    } else {
        dim3 g((N + 63) / 64, (M + 127) / 128, nz);
        gemm_mfma2<128, 64, 4><<<g, dim3(256), 0, s>>>(A, B, bias, C, c_mode, M, N, K,
            a_batch, lda, a_mod, b_batch, ldb, b_div, bias_stride, c_batch, c_row, scale, k_chunk,
            Ct, t_zbatch, t_batch, t_ld, t_colbase, t_rowdiv);
    }
}

extern "C" void kernel_launch(void* const* d_in, const int* in_sizes, int n_in,
                              void* d_out, int out_size, void* d_ws, size_t ws_size,
                              hipStream_t stream) {
    if (n_in < 26) return;
    const float* tokens     = (const float*)d_in[0];
    const float* cls_tokens = (const float*)d_in[1];
    const float* a_qkv_w  = (const float*)d_in[2];
    const float* a_qkv_b  = (const float*)d_in[3];
    const float* af_qkv_w = (const float*)d_in[4];
    const float* af_qkv_b = (const float*)d_in[5];
    const float* b_qkv_w  = (const float*)d_in[6];
    const float* b_qkv_b  = (const float*)d_in[7];
    const float* bf_qkv_w = (const float*)d_in[8];
    const float* bf_qkv_b = (const float*)d_in[9];
    const float* atW_w = (const float*)d_in[10];
    const float* atW_b = (const float*)d_in[11];
    const float* afW_w = (const float*)d_in[12];
    const float* afW_b = (const float*)d_in[13];
    const float* btW_w = (const float*)d_in[14];
    const float* btW_b = (const float*)d_in[15];
    const float* bfW_w = (const float*)d_in[16];
    const float* bfW_b = (const float*)d_in[17];
    const float* aft_w = (const float*)d_in[18];
    const float* aft_b = (const float*)d_in[19];
    const float* bft_w = (const float*)d_in[20];
    const float* bft_b = (const float*)d_in[21];
    const float* fnn1_w = (const float*)d_in[22];
    const float* fnn1_b = (const float*)d_in[23];
    const float* fnn2_w = (const float*)d_in[24];
    const float* fnn2_b = (const float*)d_in[25];
    float* outp = (float*)d_out;
    char* base = (char*)d_ws;

    // ---- workspace byte offsets (184.4MB total < 191.9MB proven) ----
    const size_t OFF_QKV = 0;            // qk interleaved (53.5MB); later ftwT+PART+FNN
    const size_t OFF_X   = 53600064;     // xbf -> O -> vfT (26.74MB)
    const size_t OFF_XT  = 80400128;     // xbT
    const size_t OFF_O   = 107200192;    // Vt -> OfT
    const size_t OFF_SP  = 134000256;    // S/P (37.75MB: feature z=32 chunk)
    const size_t OFF_AT  = 171800256;    // aTt [64][100][L]
    const size_t OFF_AF  = 175300256;    // aFt [64][100][L]
    const size_t OFF_M   = 178800256;    // Mbf [64][10000] bf16
    const size_t OFF_W   = 180080320;    // transposed weights (~4.3MB)

    auto B16 = [&](size_t off) { return (bf16*)(base + off); };
    auto F32 = [&](size_t off) { return (float*)(base + off); };

    bf16* WqT  = B16(OFF_W);                       // flat [2304][768]
    bf16* WfT  = (bf16*)(base + OFF_W + 3538944);  // flat [3L][L]
    bf16* atWt = (bf16*)(base + OFF_W + 3982848);  // [100][768]
    bf16* afWt = (bf16*)(base + OFF_W + 4136448);  // [100][768]

    auto phase = [&](int L, const float* tok, int tokRows,
                     const float* qkvW, const float* qkvB,
                     const float* fqkvW, const float* fqkvB,
                     const float* tWw, const float* tWb,
                     const float* fWw, const float* fWb,
                     const float* ftw, const float* ftb, long colOff)
    {
        const long LH = (long)L * 768;
        const long LL = (long)L * L;
        const int  L2 = 2 * L;                    // 544 or 512 (both %8==0)
        bf16* qkv = B16(OFF_QKV);                 // token: [64L][1536]; feature: [64*768][2L]
        bf16* q = qkv, *k = qkv + 768;            // token slices (lda 1536)
        bf16* qf = qkv, *kf = qkv + L;            // feature slices (lda 2L)
        bf16* xbf = B16(OFF_X);                   // -> later O, then vfT
        bf16* O   = B16(OFF_X);
        bf16* vfT = B16(OFF_X);
        bf16* xbT = B16(OFF_XT);
        bf16* Vt  = B16(OFF_O);                   // -> later OfT
        bf16* OfT = B16(OFF_O);
        bf16* SP  = B16(OFF_SP);
        bf16* aTt = B16(OFF_AT);
        bf16* aFt = B16(OFF_AF);
        bf16* Mbf = B16(OFF_M);
        bf16* ftwT  = B16(OFF_QKV);                 // [1000][10000], qkv dead by then
        float* PART = F32(OFF_QKV + 20000064);      // 32 x [64][1000] f32
        const int Lg = (L + 31) / 32;
        const float rsH = 1.0f / sqrtf(768.0f);
        const float rsL = 1.0f / sqrtf((float)L);

        // fused convert (xbf + xbT in one pass) / weight transposes
        convert_dual<<<dim3(24, Lg, 64), 256, 0, stream>>>(tok, xbf, xbT, L, tokRows);
        transpose_to_bf16<float><<<dim3(24, 24, 3), 256, 0, stream>>>(qkvW, WqT, 768, 768, 768, 589824, 768, 589824);
        transpose_to_bf16<float><<<dim3(Lg, Lg, 3), 256, 0, stream>>>(fqkvW, WfT, L, L, L, LL, L, LL);
        transpose_to_bf16<float><<<dim3(4, 24, 1), 256, 0, stream>>>(tWw, atWt, 768, 100, 100, 0, 768, 0);
        transpose_to_bf16<float><<<dim3(4, 24, 1), 256, 0, stream>>>(fWw, afWt, 768, 100, 100, 0, 768, 0);

        // ---- token branch: merged QKV, mode 2, BN=256 (colbase 1536 = 6 x 256)
        //      qk cols -> qkv[64L][1536]; v cols -> Vt[b][h][l] transposed ----
        mfma_launch(stream, 256, xbf, WqT, qkvB, qkv, 2, 64 * L, 2304, 768,
                    0, 768, 1, 0, 768, 1, 0, 0, 1536, 1.0f, 1, 0,
                    Vt, 0, LH, L, 1536, L);
        mfma_launch(stream, 64, q, k, nullptr, SP, 0, L, L, 768,
                    (long)L * 1536, 1536, 64, (long)L * 1536, 1536, 1, 0, LL, L, rsH, 64);
        softmax_rows_bf16<<<dim3((unsigned)((64L * L + 3) / 4)), 256, 0, stream>>>(SP, 64L * L, L);
        mfma_launch(stream, 256, SP, Vt, nullptr, O, 0, L, 768, L,       // O overwrites xbf (dead)
                    LL, L, 64, LH, L, 1, 0, LH, 768, 1.0f, 64);
        mfma_launch(stream, 64, O, atWt, tWb, nullptr, 3, 64 * L, 100, 768,  // aT -> aTt transposed
                    0, 768, 1, 0, 768, 1, 0, 0, 100, 1.0f, 1, 0,
                    aTt, 0, (long)100 * L, L, 0, L);

        // ---- feature branch: qk_f (normal) + v_f (mode-3 -> vfT[b][l][h], BN=64) ----
        mfma_launch(stream, 128, xbT, WfT, fqkvB, qkv, 0, 64 * 768, L2, L,
                    0, L, 1, 0, L, 1, 0, 0, L2, 1.0f, 1);
        mfma_launch(stream, 64, xbT, WfT + (long)L2 * L, fqkvB + L2, nullptr, 3, 64 * 768, L, L,
                    0, L, 1, 0, L, 1, 0, 0, 0, 1.0f, 1, 0,
                    vfT, 0, LH, 768, 0, 768);                     // vfT overwrites O (dead)
        for (int c = 0; c < 2; ++c) {   // 32-batch chunks (S chunk 37.7MB, L3-resident)
            long coA = (long)c * 32 * 768 * L2;
            long coV = (long)c * 32 * LH;
            mfma_launch(stream, 256, qf + coA, kf + coA, nullptr, SP, 0, 768, 768, L,
                        768L * L2, L2, 32, 768L * L2, L2, 1, 0, 589824, 768, rsL, 32);
            softmax_rows_bf16<<<dim3(32 * 768 / 4), 256, 0, stream>>>(SP, 32L * 768, 768);
            // PV_f swapped: OfT[l][h] = sum_{h'} vfT[l][h'] * P[h][h']  (mode 0)
            mfma_launch(stream, 256, vfT + coV, SP, nullptr, OfT + coV, 0, L, 768, 768,
                        LH, 768, 32, 589824, 768, 1, 0, LH, 768, 1.0f, 32);
        }
        mfma_launch(stream, 64, OfT, afWt, fWb, nullptr, 3, 64 * L, 100, 768,  // aF -> aFt transposed
                    0, 768, 1, 0, 768, 1, 0, 0, 100, 1.0f, 1, 0,
                    aFt, 0, (long)100 * L, L, 0, L);

        // ---- einsum + final projection ----
        mfma_launch(stream, 128, aTt, aFt, nullptr, Mbf, 0, 100, 100, L,
                    (long)100 * L, L, 64, (long)100 * L, L, 1, 0, 10000, 100, 1.0f, 64);
        transpose_to_bf16<float><<<dim3(32, 313, 1), 256, 0, stream>>>(ftw, ftwT, 10000, 1000, 1000, 0, 10000, 0);
        mfma_launch(stream, 128, Mbf, ftwT, nullptr, PART, 1, 64, 1000, 10000,
                    0, 10000, 1, 0, 10000, 1, 0, 64000, 1000, 1.0f, 32, 320);
        reduce_partials<<<dim3((64 * 1000 + 255) / 256), 256, 0, stream>>>(
            PART, ftb, outp, 32, 64, 1000, 2003, colOff);
    };

    phase(272, tokens,     273, a_qkv_w, a_qkv_b, af_qkv_w, af_qkv_b,
          atW_w, atW_b, afW_w, afW_b, aft_w, aft_b, 3);
    phase(256, cls_tokens, 257, b_qkv_w, b_qkv_b, bf_qkv_w, bf_qkv_b,
          btW_w, btW_b, bfW_w, bfW_b, bft_w, bft_b, 1003);

    // ---- FNN head via MFMA (OFF_QKV region is dead now) ----
    bf16* hT     = B16(OFF_QKV);                   // [64][1536]
    bf16* fnn1T  = (bf16*)(base + OFF_QKV + 262144);   // [768][1536]
    float* PARTF = F32(OFF_QKV + 2621504);         // 6 x [64][768]
    float* h1    = F32(OFF_QKV + 3801216);         // [64][768]
    build_h<<<dim3((64 * 1536 + 255) / 256), 256, 0, stream>>>(tokens, cls_tokens, hT, 273, 257);
    transpose_to_bf16<float><<<dim3(24, 48, 1), 256, 0, stream>>>(fnn1_w, fnn1T, 1536, 768, 768, 0, 1536, 0);
    mfma_launch(stream, 128, hT, fnn1T, nullptr, PARTF, 1, 64, 768, 1536,
                0, 1536, 1, 0, 1536, 1, 0, 49152, 768, 1.0f, 6, 256);
    reduce_partials<<<dim3((64 * 768 + 255) / 256), 256, 0, stream>>>(
        PARTF, fnn1_b, h1, 6, 64, 768, 768, 0);
    predicts_kernel<<<dim3(1), 256, 0, stream>>>(h1, fnn2_w, fnn2_b, outp);
}

// Round 20
// 890.952 us; speedup vs baseline: 1.0670x; 1.0228x over previous
//
#include <hip/hip_runtime.h>
#include <hip/hip_bf16.h>
#include <math.h>

typedef __hip_bfloat16 bf16;
typedef __attribute__((ext_vector_type(8))) short bf16x8;
typedef __attribute__((ext_vector_type(4))) float f32x4;

typedef const void __attribute__((address_space(1)))* gptr_t;
typedef void __attribute__((address_space(3)))* lptr_t;

static __device__ __forceinline__ void gload16(const void* g, void* l) {
    __builtin_amdgcn_global_load_lds((gptr_t)g, (lptr_t)l, 16, 0, 0);
}

static __device__ __forceinline__ float tofl(float x) { return x; }
static __device__ __forceinline__ float tofl(bf16 x) { return __bfloat162float(x); }
static __device__ __forceinline__ float bfbits(unsigned short u) {
    return __uint_as_float(((unsigned)u) << 16);
}

// ---------------------------------------------------------------------------
// Batched MFMA GEMM, operands K-contiguous ("TN"), global_load_lds staged,
// triple-buffered counted-vmcnt K-loop, XCD-bijective block swizzle,
// XOR bank-swizzle on staging. Wave grid 2 x (NWAVE/2); per-wave tile
// (BM/2) x (BN/(NWAVE/2)). Configs: (128,64,4) (128,128,4) (128,256,8).
// (256-tile BM rejected: 1 block/CU starves the 2-barrier skeleton, r18.)
//
// K%32!=0: last K-step over-reads <=16 elements past the row; BOTH A and B
// fragments are zero-masked for invalid chunks (0 x NaN = NaN otherwise).
//
//   C[z,i,j] = scale*sum_k A[(z%a_mod)*a_batch + i*lda + k]
//                    * B[(z/b_div)*b_batch + j*ldb + k] + bias[(z/b_div)*bs + j]
// k_chunk>0: z indexes K-split chunks (f32 partials).
//
// c_mode: 0 = bf16 normal store; 1 = f32 direct store;
//         2 = per-tile: tiles with j0 < t_colbase normal, j0 >= t_colbase
//             transposed (t_colbase MUST be a multiple of BN -> no straddle);
//         3 = transposed-only.
// Transposed tile: LDS C-tile Cst[col][row] pitch BM+8 (uint2 writes, uint4
// reads, both bank-spread). Mapping: row i -> (b2=i/t_rowdiv, rr=i%t_rowdiv);
//   Ct[bz*t_zbatch + b2*t_batch + (j-t_colbase)*t_ld + rr]
// (16B packs of 8 rows; requires M%8==0, t_rowdiv%8==0, t_ld%8==0).
// Requires lda%8==0, ldb%8==0, 16B-aligned bases, +64B slack per operand
// buffer. Pad rows clamped.
// ---------------------------------------------------------------------------
template<int BM, int BN, int NWAVE>
__global__ __launch_bounds__(NWAVE * 64)
void gemm_mfma2(const bf16* __restrict__ A, const bf16* __restrict__ B,
                const float* __restrict__ bias, void* __restrict__ C, int c_mode,
                int M, int N, int K,
                long a_batch, long lda, int a_mod,
                long b_batch, long ldb, int b_div,
                long bias_stride, long c_batch, long c_row,
                float scale, int k_chunk,
                bf16* __restrict__ Ct, long t_zbatch, long t_batch, long t_ld,
                int t_colbase, int t_rowdiv)
{
    constexpr int NT = NWAVE * 64;               // threads
    constexpr int WC = NWAVE / 2;                // wave cols (grid is 2 x WC)
    constexpr int WM = BM / 2;                   // per-wave M span
    constexpr int WN = BN / WC;                  // per-wave N span
    constexpr int FM = WM / 16, FN = WN / 16;
    constexpr int AL = BM / (NWAVE * 16);        // A gloads per wave
    constexpr int NBB = BN / (NWAVE * 16);       // B gloads per wave
    constexpr int P = AL + NBB;                  // gloads per wave per iter
    constexpr int CP  = BN + 4;                  // normal C-tile pitch (bf16)
    constexpr int CPT = BM + 8;                  // transposed C-tile pitch
    constexpr int BUFS = (BM + BN) * 32;         // shorts per stage buffer
    constexpr int NBUF = 3;
    constexpr int ABSZ = NBUF * BUFS * 2;
    constexpr int CSZ  = BM * CP * 2;
    constexpr int CTSZ = BN * CPT * 2;
    constexpr int CMAX = (CSZ > CTSZ) ? CSZ : CTSZ;
    constexpr int SMSZ = (CMAX > ABSZ) ? CMAX : ABSZ;
    __shared__ __align__(16) char smem[SMSZ];
    short* SA = (short*)smem;

    // ---- bijective XCD chunk swizzle (m204) ----
    const int gx = gridDim.x, gy = gridDim.y;
    const int nwg = gx * gy * (int)gridDim.z;
    const int orig = blockIdx.x + gx * (blockIdx.y + gy * blockIdx.z);
    const int qv = nwg >> 3, rv = nwg & 7;
    const int xcd = orig & 7, pos = orig >> 3;
    const int wg = (xcd < rv ? xcd * (qv + 1) : rv * (qv + 1) + (xcd - rv) * qv) + pos;
    const int bx = wg % gx, by = (wg / gx) % gy, bz = wg / (gx * gy);

    const int tid = threadIdx.x, w = tid >> 6, lane = tid & 63;
    const int wr = w / WC, wc = w % WC, lrow = lane & 15, lch = lane >> 4;
    const bf16* Ab = A + (long)(bz % a_mod) * a_batch;
    const bf16* Bb = B + (long)(bz / b_div) * b_batch;
    const int i0 = by * BM, j0 = bx * BN;

    int kstart = 0, kend = K;
    if (k_chunk > 0) {
        kstart = bz * k_chunk;
        kend = kstart + k_chunk; if (kend > K) kend = K;
    }

    f32x4 acc[FM][FN];
#pragma unroll
    for (int m = 0; m < FM; ++m)
#pragma unroll
        for (int n = 0; n < FN; ++n) acc[m][n] = (f32x4){0.f, 0.f, 0.f, 0.f};

    const int srow = lane >> 2;                          // staging row-in-16
    const int schunk = ((lane & 3) ^ (srow & 3)) * 8;    // XOR-swizzled source chunk
    const int nt = (kend - kstart + 31) >> 5;
    const bool has_tail = ((kend - kstart) & 31) != 0;
    const bf16x8 zero8 = {0, 0, 0, 0, 0, 0, 0, 0};

    // ---- hoisted staging pointers (row-clamped) + LDS dest offsets ----
    const bf16* agp[AL];
    int aoff[AL];
#pragma unroll
    for (int u = 0; u < AL; ++u) {
        int row = w * (BM / NWAVE) + u * 16 + srow;
        long gr = i0 + row; if (gr > M - 1) gr = M - 1;
        agp[u] = Ab + gr * lda + schunk;
        aoff[u] = (w * (BM / NWAVE) + u * 16) * 32;
    }
    const bf16* bgp[NBB];
    int boff[NBB];
#pragma unroll
    for (int u = 0; u < NBB; ++u) {
        int row = w * (BN / NWAVE) + u * 16 + srow;
        long gr = j0 + row; if (gr > N - 1) gr = N - 1;
        bgp[u] = Bb + gr * ldb + schunk;
        boff[u] = BM * 32 + (w * (BN / NWAVE) + u * 16) * 32;
    }
    // ---- hoisted fragment LDS read offsets (loop-invariant) ----
    const int rsw = (lch ^ (lane & 3)) * 8;   // row&3 == lane&3 for all frags
    int aro[FM], bro[FN];
#pragma unroll
    for (int m = 0; m < FM; ++m) aro[m] = (wr * WM + m * 16 + lrow) * 32 + rsw;
#pragma unroll
    for (int n = 0; n < FN; ++n) bro[n] = BM * 32 + (wc * WN + n * 16 + lrow) * 32 + rsw;

    auto stage = [&](int buf, int k0) {
        short* base = SA + buf * BUFS;
#pragma unroll
        for (int u = 0; u < AL; ++u) gload16(agp[u] + k0, base + aoff[u]);
#pragma unroll
        for (int u = 0; u < NBB; ++u) gload16(bgp[u] + k0, base + boff[u]);
    };

    stage(0, kstart);
    if (nt > 1) stage(1, kstart + 32);

    for (int t = 0; t < nt; ++t) {
        if (t + 1 < nt)
            asm volatile("s_waitcnt vmcnt(%0)" :: "i"(P) : "memory");  // tile t landed, t+1 in flight
        else
            asm volatile("s_waitcnt vmcnt(0)" ::: "memory");
        __builtin_amdgcn_s_barrier();
        __builtin_amdgcn_sched_barrier(0);

        if (t + 2 < nt) stage((t + 2) % NBUF, kstart + (t + 2) * 32);

        short* buf = SA + (t % NBUF) * BUFS;
        bf16x8 af[FM], bfv[FN];
        if (has_tail && t == nt - 1) {      // wave-uniform branch: masked tail
            const int k0 = kstart + t * 32;
            const bool kok = (k0 + lch * 8) < kend;
#pragma unroll
            for (int m = 0; m < FM; ++m) {
                af[m] = *(const bf16x8*)&buf[aro[m]];
                if (!kok) af[m] = zero8;
            }
#pragma unroll
            for (int n = 0; n < FN; ++n) {
                bfv[n] = *(const bf16x8*)&buf[bro[n]];
                if (!kok) bfv[n] = zero8;   // B mask essential: 0 x NaN = NaN
            }
        } else {                            // main path: no masking
#pragma unroll
            for (int m = 0; m < FM; ++m) af[m] = *(const bf16x8*)&buf[aro[m]];
#pragma unroll
            for (int n = 0; n < FN; ++n) bfv[n] = *(const bf16x8*)&buf[bro[n]];
        }
#pragma unroll
        for (int m = 0; m < FM; ++m)
#pragma unroll
            for (int n = 0; n < FN; ++n)
                acc[m][n] = __builtin_amdgcn_mfma_f32_16x16x32_bf16(af[m], bfv[n], acc[m][n], 0, 0, 0);
    }

    const float* bp = bias ? (bias + (long)(bz / b_div) * bias_stride) : nullptr;

    if (c_mode == 1) {  // small f32 partials: direct scalar stores
#pragma unroll
        for (int n = 0; n < FN; ++n) {
            int cc = j0 + wc * WN + n * 16 + lrow;
            if (cc >= N) continue;
            float bv = bp ? bp[cc] : 0.f;
#pragma unroll
            for (int m = 0; m < FM; ++m) {
                int rbase = i0 + wr * WM + m * 16 + lch * 4;
#pragma unroll
                for (int j = 0; j < 4; ++j) {
                    int r = rbase + j;
                    if (r >= M) continue;
                    ((float*)C)[(long)bz * c_batch + (long)r * c_row + cc] = acc[m][n][j] * scale + bv;
                }
            }
        }
        return;
    }

    __builtin_amdgcn_s_barrier();   // K-loop done in all waves before smem reuse
    short* Cs = (short*)smem;
    const bool do_tr = (c_mode == 3) || (c_mode == 2 && j0 >= t_colbase);

    if (!do_tr) {
        // ---- normal layout [row][col] pitch CP; coalesced row stores ----
#pragma unroll
        for (int n = 0; n < FN; ++n) {
            int col = wc * WN + n * 16 + lrow;
            float bv = bp ? bp[(j0 + col < N) ? (j0 + col) : (N - 1)] : 0.f;
#pragma unroll
            for (int m = 0; m < FM; ++m) {
                int rb = wr * WM + m * 16 + lch * 4;
#pragma unroll
                for (int j = 0; j < 4; ++j) {
                    bf16 hv = __float2bfloat16(acc[m][n][j] * scale + bv);
                    Cs[(rb + j) * CP + col] = *(short*)&hv;
                }
            }
        }
        __syncthreads();
        constexpr int CHR = BN / 8;
        constexpr int CH = (BM * BN) / (NT * 8);
#pragma unroll
        for (int u = 0; u < CH; ++u) {
            int e = tid + u * NT;
            int row = e / CHR, c8 = (e % CHR) * 8;
            int r = i0 + row, cc = j0 + c8;
            if (r >= M) continue;
            bf16* dst = (bf16*)C + (long)bz * c_batch + (long)r * c_row + cc;
            if (cc + 8 <= N) {
                *(uint4*)dst = *(uint4*)&Cs[row * CP + c8];
            } else {
                for (int t2 = 0; t2 < 8; ++t2)
                    if (cc + t2 < N) dst[t2] = *(bf16*)&Cs[row * CP + c8 + t2];
            }
        }
    } else {
        // ---- transposed tile: Cst[col][row] pitch CPT ----
#pragma unroll
        for (int n = 0; n < FN; ++n) {
            int col = wc * WN + n * 16 + lrow;
            float bv = bp ? bp[(j0 + col < N) ? (j0 + col) : (N - 1)] : 0.f;
#pragma unroll
            for (int m = 0; m < FM; ++m) {
                int rb = wr * WM + m * 16 + lch * 4;
                uint2 pk;
                unsigned short* ps = (unsigned short*)&pk;
#pragma unroll
                for (int j = 0; j < 4; ++j) {
                    bf16 hv = __float2bfloat16(acc[m][n][j] * scale + bv);
                    ps[j] = *(unsigned short*)&hv;
                }
                *(uint2*)&Cs[col * CPT + rb] = pk;
            }
        }
        __syncthreads();
        constexpr int CHT = (BN * (BM / 8)) / NT;
#pragma unroll
        for (int u = 0; u < CHT; ++u) {
            int e = tid + u * NT;
            int col = e / (BM / 8), r8 = e % (BM / 8);
            int j = j0 + col;
            int rb = i0 + r8 * 8;
            if (j >= N || rb >= M) continue;
            int b2 = rb / t_rowdiv;
            int rr = rb - b2 * t_rowdiv;
            long idx = (long)bz * t_zbatch + (long)b2 * t_batch + (long)(j - t_colbase) * t_ld + rr;
            *(uint4*)&Ct[idx] = *(uint4*)&Cs[col * CPT + r8 * 8];
        }
    }
}

// Tiled transpose with convert: dst[z][c][r] = src[z][r][c]
template<typename ST>
__global__ __launch_bounds__(256)
void transpose_to_bf16(const ST* __restrict__ src, bf16* __restrict__ dst,
                       int R, int C, long s_ld, long s_batch, long d_ld, long d_batch)
{
    __shared__ float t[32][33];
    const int z = blockIdx.z;
    const int tx = threadIdx.x & 31, ty = threadIdx.x >> 5;
    const int r0 = blockIdx.y << 5, c0 = blockIdx.x << 5;
    const ST* sb = src + (long)z * s_batch;
#pragma unroll
    for (int i = 0; i < 4; ++i) {
        int r = r0 + ty + i * 8, c = c0 + tx;
        if (r < R && c < C) t[ty + i * 8][tx] = tofl(sb[(long)r * s_ld + c]);
    }
    __syncthreads();
    bf16* db = dst + (long)z * d_batch;
#pragma unroll
    for (int i = 0; i < 4; ++i) {
        int dr = c0 + ty + i * 8, dc = r0 + tx;
        if (dr < C && dc < R) db[(long)dr * d_ld + dc] = __float2bfloat16(t[tx][ty + i * 8]);
    }
}

// Batched f32->bf16 transpose: up to 4 independent transposes in one launch.
struct TD {
    const float* src; bf16* dst;
    int R, C; long s_ld, s_batch, d_ld, d_batch;
    int nbx, nby, nz, off;
};
struct TDs { TD d[4]; int nd; };

__global__ __launch_bounds__(256)
void transpose_multi(TDs td)
{
    __shared__ float t[32][33];
    const int gb = blockIdx.x;
    int di = 0;
#pragma unroll
    for (int i = 1; i < 4; ++i)
        if (i < td.nd && gb >= td.d[i].off) di = i;
    const TD D = td.d[di];
    const int local = gb - D.off;
    const int per = D.nbx * D.nby;
    const int z = local / per, rem = local - z * per;
    const int by = rem / D.nbx, bxx = rem - by * D.nbx;
    const int tx = threadIdx.x & 31, ty = threadIdx.x >> 5;
    const int r0 = by << 5, c0 = bxx << 5;
    const float* sb = D.src + (long)z * D.s_batch;
#pragma unroll
    for (int i = 0; i < 4; ++i) {
        int r = r0 + ty + i * 8, c = c0 + tx;
        if (r < D.R && c < D.C) t[ty + i * 8][tx] = sb[(long)r * D.s_ld + c];
    }
    __syncthreads();
    bf16* db = D.dst + (long)z * D.d_batch;
#pragma unroll
    for (int i = 0; i < 4; ++i) {
        int dr = c0 + ty + i * 8, dc = r0 + tx;
        if (dr < D.C && dc < D.R) db[(long)dr * D.d_ld + dc] = __float2bfloat16(t[tx][ty + i * 8]);
    }
}

// Fused: read tokens f32 [b][l+1][h], write xbf[b][l][h] AND xbT[b][h][l] (bf16).
__global__ __launch_bounds__(256)
void convert_dual(const float* __restrict__ src, bf16* __restrict__ xbf,
                  bf16* __restrict__ xbT, int L, int tokRows)
{
    __shared__ float t[32][33];
    const int tx = threadIdx.x & 31, ty = threadIdx.x >> 5;
    const int l0 = blockIdx.y << 5, h0 = blockIdx.x << 5;
    const float* sb = src + (long)blockIdx.z * tokRows * 768 + 768;
    bf16* xb = xbf + (long)blockIdx.z * L * 768;
    bf16* xt = xbT + (long)blockIdx.z * L * 768;
#pragma unroll
    for (int i = 0; i < 4; ++i) {
        int l = l0 + ty + i * 8, h = h0 + tx;
        float v = (l < L) ? sb[(long)l * 768 + h] : 0.f;
        t[ty + i * 8][tx] = v;
        if (l < L) xb[(long)l * 768 + h] = __float2bfloat16(v);
    }
    __syncthreads();
#pragma unroll
    for (int i = 0; i < 4; ++i) {
        int h = h0 + ty + i * 8, l = l0 + tx;
        if (l < L) xt[(long)h * L + l] = __float2bfloat16(t[tx][ty + i * 8]);
    }
}

// hT[b][0:768]=tokens[b][0][:], hT[b][768:1536]=cls[b][0][:]
__global__ __launch_bounds__(256)
void build_h(const float* __restrict__ tokens, const float* __restrict__ cls,
             bf16* __restrict__ hT, int tokRows, int clsRows)
{
    int idx = blockIdx.x * 256 + threadIdx.x;
    if (idx >= 64 * 1536) return;
    int b = idx / 1536, c = idx % 1536;
    float v = (c < 768) ? tokens[(long)b * tokRows * 768 + c]
                        : cls[(long)b * clsRows * 768 + (c - 768)];
    hT[idx] = __float2bfloat16(v);
}

// In-place bf16 row softmax (f32 math), one wave per row, vectorized uint4.
__global__ __launch_bounds__(256)
void softmax_rows_bf16(bf16* __restrict__ S, long nrows, int rowlen)
{
    long row = (long)blockIdx.x * 4 + (threadIdx.x >> 6);
    if (row >= nrows) return;
    int lane = threadIdx.x & 63;
    uint4* p = (uint4*)(S + row * (long)rowlen);
    const int nch = rowlen >> 3;
    float v[2][8];
    float m = -3.4e38f;
#pragma unroll
    for (int i = 0; i < 2; ++i) {
        int c = lane + i * 64;
        if (c < nch) {
            uint4 raw = p[c];
            unsigned short* u = (unsigned short*)&raw;
#pragma unroll
            for (int j = 0; j < 8; ++j) { v[i][j] = bfbits(u[j]); m = fmaxf(m, v[i][j]); }
        }
    }
#pragma unroll
    for (int off = 32; off > 0; off >>= 1) m = fmaxf(m, __shfl_xor(m, off, 64));
    float s = 0.f;
#pragma unroll
    for (int i = 0; i < 2; ++i) {
        int c = lane + i * 64;
        if (c < nch) {
#pragma unroll
            for (int j = 0; j < 8; ++j) { v[i][j] = __expf(v[i][j] - m); s += v[i][j]; }
        }
    }
#pragma unroll
    for (int off = 32; off > 0; off >>= 1) s += __shfl_xor(s, off, 64);
    float inv = 1.f / s;
#pragma unroll
    for (int i = 0; i < 2; ++i) {
        int c = lane + i * 64;
        if (c < nch) {
            uint4 outv;
            unsigned short* u = (unsigned short*)&outv;
#pragma unroll
            for (int j = 0; j < 8; ++j) {
                bf16 hv = __float2bfloat16(v[i][j] * inv);
                u[j] = *(unsigned short*)&hv;
            }
            p[c] = outv;
        }
    }
}

// dst[i*stride + col_off + j] = bias[j] + sum_z partial[z*rows*cols + i*cols + j]
__global__ __launch_bounds__(256)
void reduce_partials(const float* __restrict__ partial, const float* __restrict__ bias,
                     float* __restrict__ dst, int nz, int rows, int cols,
                     long dst_row_stride, long dst_col_off)
{
    int idx = blockIdx.x * 256 + threadIdx.x;
    if (idx >= rows * cols) return;
    int i = idx / cols, j = idx % cols;
    float s = bias ? bias[j] : 0.f;
    long rc = (long)rows * cols;
    for (int z = 0; z < nz; ++z) s += partial[(long)z * rc + idx];
    dst[(long)i * dst_row_stride + dst_col_off + j] = s;
}

// predicts = h1 @ fnn2_w + fnn2_b -> out[:, 0:3] (row stride 2003)
__global__ __launch_bounds__(256)
void predicts_kernel(const float* __restrict__ h1, const float* __restrict__ w2,
                     const float* __restrict__ b2, float* __restrict__ out)
{
    int idx = threadIdx.x;
    if (idx >= 64 * 3) return;
    int b = idx / 3, c = idx % 3;
    float s = b2[c];
    const float* hr = h1 + (long)b * 768;
    for (int k = 0; k < 768; ++k) s = fmaf(hr[k], w2[k * 3 + c], s);
    out[(long)b * 2003 + c] = s;
}

// ---------------------------------------------------------------------------
static inline void mfma_launch(hipStream_t s, int bn,
    const bf16* A, const bf16* B, const float* bias, void* C, int c_mode,
    int M, int N, int K,
    long a_batch, long lda, int a_mod,
    long b_batch, long ldb, int b_div,
    long bias_stride, long c_batch, long c_row, float scale, int nz, int k_chunk = 0,
    bf16* Ct = nullptr, long t_zbatch = 0, long t_batch = 0, long t_ld = 0,
    int t_colbase = 0, int t_rowdiv = 8)
{
    if (bn == 256) {
        dim3 g((N + 255) / 256, (M + 127) / 128, nz);
        gemm_mfma2<128, 256, 8><<<g, dim3(512), 0, s>>>(A, B, bias, C, c_mode, M, N, K,
            a_batch, lda, a_mod, b_batch, ldb, b_div, bias_stride, c_batch, c_row, scale, k_chunk,
            Ct, t_zbatch, t_batch, t_ld, t_colbase, t_rowdiv);
    } else if (bn == 128) {
        dim3 g((N + 127) / 128, (M + 127) / 128, nz);
        gemm_mfma2<128, 128, 4><<<g, dim3(256), 0, s>>>(A, B, bias, C, c_mode, M, N, K,
            a_batch, lda, a_mod, b_batch, ldb, b_div, bias_stride, c_batch, c_row, scale, k_chunk,
            Ct, t_zbatch, t_batch, t_ld, t_colbase, t_rowdiv);
    } else {
        dim3 g((N + 63) / 64, (M + 127) / 128, nz);
        gemm_mfma2<128, 64, 4><<<g, dim3(256), 0, s>>>(A, B, bias, C, c_mode, M, N, K,
            a_batch, lda, a_mod, b_batch, ldb, b_div, bias_stride, c_batch, c_row, scale, k_chunk,
            Ct, t_zbatch, t_batch, t_ld, t_colbase, t_rowdiv);
    }
}

extern "C" void kernel_launch(void* const* d_in, const int* in_sizes, int n_in,
                              void* d_out, int out_size, void* d_ws, size_t ws_size,
                              hipStream_t stream) {
    if (n_in < 26) return;
    const float* tokens     = (const float*)d_in[0];
    const float* cls_tokens = (const float*)d_in[1];
    const float* a_qkv_w  = (const float*)d_in[2];
    const float* a_qkv_b  = (const float*)d_in[3];
    const float* af_qkv_w = (const float*)d_in[4];
    const float* af_qkv_b = (const float*)d_in[5];
    const float* b_qkv_w  = (const float*)d_in[6];
    const float* b_qkv_b  = (const float*)d_in[7];
    const float* bf_qkv_w = (const float*)d_in[8];
    const float* bf_qkv_b = (const float*)d_in[9];
    const float* atW_w = (const float*)d_in[10];
    const float* atW_b = (const float*)d_in[11];
    const float* afW_w = (const float*)d_in[12];
    const float* afW_b = (const float*)d_in[13];
    const float* btW_w = (const float*)d_in[14];
    const float* btW_b = (const float*)d_in[15];
    const float* bfW_w = (const float*)d_in[16];
    const float* bfW_b = (const float*)d_in[17];
    const float* aft_w = (const float*)d_in[18];
    const float* aft_b = (const float*)d_in[19];
    const float* bft_w = (const float*)d_in[20];
    const float* bft_b = (const float*)d_in[21];
    const float* fnn1_w = (const float*)d_in[22];
    const float* fnn1_b = (const float*)d_in[23];
    const float* fnn2_w = (const float*)d_in[24];
    const float* fnn2_b = (const float*)d_in[25];
    float* outp = (float*)d_out;
    char* base = (char*)d_ws;

    // ---- workspace byte offsets (184.4MB total < 191.9MB proven) ----
    const size_t OFF_QKV = 0;            // qk interleaved (53.5MB); later ftwT+PART+FNN
    const size_t OFF_X   = 53600064;     // xbf -> O -> vfT (26.74MB)
    const size_t OFF_XT  = 80400128;     // xbT
    const size_t OFF_O   = 107200192;    // Vt -> OfT
    const size_t OFF_SP  = 134000256;    // S/P (37.75MB: feature z=32 chunk)
    const size_t OFF_AT  = 171800256;    // aTt [64][100][L]
    const size_t OFF_AF  = 175300256;    // aFt [64][100][L]
    const size_t OFF_M   = 178800256;    // Mbf [64][10000] bf16
    const size_t OFF_W   = 180080320;    // transposed weights (~4.3MB)

    auto B16 = [&](size_t off) { return (bf16*)(base + off); };
    auto F32 = [&](size_t off) { return (float*)(base + off); };

    bf16* WqT  = B16(OFF_W);                       // flat [2304][768]
    bf16* WfT  = (bf16*)(base + OFF_W + 3538944);  // flat [3L][L]
    bf16* atWt = (bf16*)(base + OFF_W + 3982848);  // [100][768]
    bf16* afWt = (bf16*)(base + OFF_W + 4136448);  // [100][768]

    auto phase = [&](int L, const float* tok, int tokRows,
                     const float* qkvW, const float* qkvB,
                     const float* fqkvW, const float* fqkvB,
                     const float* tWw, const float* tWb,
                     const float* fWw, const float* fWb,
                     const float* ftw, const float* ftb, long colOff)
    {
        const long LH = (long)L * 768;
        const long LL = (long)L * L;
        const int  L2 = 2 * L;                    // 544 or 512 (both %8==0)
        bf16* qkv = B16(OFF_QKV);                 // token: [64L][1536]; feature: [64*768][2L]
        bf16* q = qkv, *k = qkv + 768;            // token slices (lda 1536)
        bf16* qf = qkv, *kf = qkv + L;            // feature slices (lda 2L)
        bf16* xbf = B16(OFF_X);                   // -> later O, then vfT
        bf16* O   = B16(OFF_X);
        bf16* vfT = B16(OFF_X);
        bf16* xbT = B16(OFF_XT);
        bf16* Vt  = B16(OFF_O);                   // -> later OfT
        bf16* OfT = B16(OFF_O);
        bf16* SP  = B16(OFF_SP);
        bf16* aTt = B16(OFF_AT);
        bf16* aFt = B16(OFF_AF);
        bf16* Mbf = B16(OFF_M);
        bf16* ftwT  = B16(OFF_QKV);                 // [1000][10000], qkv dead by then
        float* PART = F32(OFF_QKV + 20000064);      // 16 x [64][1000] f32
        const int Lg = (L + 31) / 32;
        const float rsH = 1.0f / sqrtf(768.0f);
        const float rsL = 1.0f / sqrtf((float)L);

        // fused convert (xbf + xbT in one pass) + batched weight transposes (1 launch)
        convert_dual<<<dim3(24, Lg, 64), 256, 0, stream>>>(tok, xbf, xbT, L, tokRows);
        {
            TDs td;
            int o0 = 0;
            td.d[0] = { qkvW, WqT, 768, 768, 768, 589824, 768, 589824, 24, 24, 3, o0 };
            int o1 = o0 + 24 * 24 * 3;
            td.d[1] = { fqkvW, WfT, L, L, (long)L, LL, (long)L, LL, Lg, Lg, 3, o1 };
            int o2 = o1 + Lg * Lg * 3;
            td.d[2] = { tWw, atWt, 768, 100, 100, 0, 768, 0, 4, 24, 1, o2 };
            int o3 = o2 + 4 * 24;
            td.d[3] = { fWw, afWt, 768, 100, 100, 0, 768, 0, 4, 24, 1, o3 };
            int tot = o3 + 4 * 24;
            td.nd = 4;
            transpose_multi<<<dim3(tot), 256, 0, stream>>>(td);
        }

        // ---- token branch: merged QKV, mode 2, BN=256 (colbase 1536 = 6 x 256)
        //      qk cols -> qkv[64L][1536]; v cols -> Vt[b][h][l] transposed ----
        mfma_launch(stream, 256, xbf, WqT, qkvB, qkv, 2, 64 * L, 2304, 768,
                    0, 768, 1, 0, 768, 1, 0, 0, 1536, 1.0f, 1, 0,
                    Vt, 0, LH, L, 1536, L);
        mfma_launch(stream, 64, q, k, nullptr, SP, 0, L, L, 768,
                    (long)L * 1536, 1536, 64, (long)L * 1536, 1536, 1, 0, LL, L, rsH, 64);
        softmax_rows_bf16<<<dim3((unsigned)((64L * L + 3) / 4)), 256, 0, stream>>>(SP, 64L * L, L);
        mfma_launch(stream, 256, SP, Vt, nullptr, O, 0, L, 768, L,       // O overwrites xbf (dead)
                    LL, L, 64, LH, L, 1, 0, LH, 768, 1.0f, 64);
        mfma_launch(stream, 64, O, atWt, tWb, nullptr, 3, 64 * L, 100, 768,  // aT -> aTt transposed
                    0, 768, 1, 0, 768, 1, 0, 0, 100, 1.0f, 1, 0,
                    aTt, 0, (long)100 * L, L, 0, L);

        // ---- feature branch: qk_f (normal) + v_f (mode-3 -> vfT[b][l][h], BN=64) ----
        mfma_launch(stream, 128, xbT, WfT, fqkvB, qkv, 0, 64 * 768, L2, L,
                    0, L, 1, 0, L, 1, 0, 0, L2, 1.0f, 1);
        mfma_launch(stream, 64, xbT, WfT + (long)L2 * L, fqkvB + L2, nullptr, 3, 64 * 768, L, L,
                    0, L, 1, 0, L, 1, 0, 0, 0, 1.0f, 1, 0,
                    vfT, 0, LH, 768, 0, 768);                     // vfT overwrites O (dead)
        for (int c = 0; c < 2; ++c) {   // 32-batch chunks (S chunk 37.7MB, L3-resident)
            long coA = (long)c * 32 * 768 * L2;
            long coV = (long)c * 32 * LH;
            mfma_launch(stream, 256, qf + coA, kf + coA, nullptr, SP, 0, 768, 768, L,
                        768L * L2, L2, 32, 768L * L2, L2, 1, 0, 589824, 768, rsL, 32);
            softmax_rows_bf16<<<dim3(32 * 768 / 4), 256, 0, stream>>>(SP, 32L * 768, 768);
            // PV_f swapped: OfT[l][h] = sum_{h'} vfT[l][h'] * P[h][h']  (mode 0)
            mfma_launch(stream, 256, vfT + coV, SP, nullptr, OfT + coV, 0, L, 768, 768,
                        LH, 768, 32, 589824, 768, 1, 0, LH, 768, 1.0f, 32);
        }
        mfma_launch(stream, 64, OfT, afWt, fWb, nullptr, 3, 64 * L, 100, 768,  // aF -> aFt transposed
                    0, 768, 1, 0, 768, 1, 0, 0, 100, 1.0f, 1, 0,
                    aFt, 0, (long)100 * L, L, 0, L);

        // ---- einsum + final projection (split-K 16 x 640) ----
        mfma_launch(stream, 128, aTt, aFt, nullptr, Mbf, 0, 100, 100, L,
                    (long)100 * L, L, 64, (long)100 * L, L, 1, 0, 10000, 100, 1.0f, 64);
        transpose_to_bf16<float><<<dim3(32, 313, 1), 256, 0, stream>>>(ftw, ftwT, 10000, 1000, 1000, 0, 10000, 0);
        mfma_launch(stream, 128, Mbf, ftwT, nullptr, PART, 1, 64, 1000, 10000,
                    0, 10000, 1, 0, 10000, 1, 0, 64000, 1000, 1.0f, 16, 640);
        reduce_partials<<<dim3((64 * 1000 + 255) / 256), 256, 0, stream>>>(
            PART, ftb, outp, 16, 64, 1000, 2003, colOff);
    };

    phase(272, tokens,     273, a_qkv_w, a_qkv_b, af_qkv_w, af_qkv_b,
          atW_w, atW_b, afW_w, afW_b, aft_w, aft_b, 3);
    phase(256, cls_tokens, 257, b_qkv_w, b_qkv_b, bf_qkv_w, bf_qkv_b,
          btW_w, btW_b, bfW_w, bfW_b, bft_w, bft_b, 1003);

    // ---- FNN head via MFMA (OFF_QKV region is dead now) ----
    bf16* hT     = B16(OFF_QKV);                   // [64][1536]
    bf16* fnn1T  = (bf16*)(base + OFF_QKV + 262144);   // [768][1536]
    float* PARTF = F32(OFF_QKV + 2621504);         // 6 x [64][768]
    float* h1    = F32(OFF_QKV + 3801216);         // [64][768]
    build_h<<<dim3((64 * 1536 + 255) / 256), 256, 0, stream>>>(tokens, cls_tokens, hT, 273, 257);
    transpose_to_bf16<float><<<dim3(24, 48, 1), 256, 0, stream>>>(fnn1_w, fnn1T, 1536, 768, 768, 0, 1536, 0);
    mfma_launch(stream, 128, hT, fnn1T, nullptr, PARTF, 1, 64, 768, 1536,
                0, 1536, 1, 0, 1536, 1, 0, 49152, 768, 1.0f, 6, 256);
    reduce_partials<<<dim3((64 * 768 + 255) / 256), 256, 0, stream>>>(
        PARTF, fnn1_b, h1, 6, 64, 768, 768, 0);
    predicts_kernel<<<dim3(1), 256, 0, stream>>>(h1, fnn2_w, fnn2_b, outp);
}